// Round 4
// baseline (5953.547 us; speedup 1.0000x reference)
//
#include <hip/hip_runtime.h>
#include <stdint.h>

typedef __attribute__((ext_vector_type(4))) int i32x4;

typedef const __attribute__((address_space(1))) void gvoid_t;
typedef __attribute__((address_space(3))) void lvoid_t;

#define GLD16(g, l) __builtin_amdgcn_global_load_lds((gvoid_t*)(g), (lvoid_t*)(l), 16, 0, 0)
#define FENCE() asm volatile("" ::: "memory")
#define BARRIER() do { FENCE(); __builtin_amdgcn_s_barrier(); FENCE(); } while (0)

__device__ inline int q1mul(float x, float r) {
    return (int)fminf(fmaxf(rintf(x * r), -128.f), 127.f);
}
__device__ inline int q1div(float x, float s) {
    return (int)fminf(fmaxf(rintf(x / s), -128.f), 127.f);
}
__device__ inline int pack4(float4 v, float r) {
    return (q1mul(v.x, r) & 255) | ((q1mul(v.y, r) & 255) << 8) |
           ((q1mul(v.z, r) & 255) << 16) | ((q1mul(v.w, r) & 255) << 24);
}

// ---------------- global absmax ----------------
__global__ void k_absmax(const float* __restrict__ x, size_t n4, unsigned int* __restrict__ out) {
    size_t S = (size_t)gridDim.x * blockDim.x;
    size_t i = (size_t)blockIdx.x * blockDim.x + threadIdx.x;
    const float4* x4 = (const float4*)x;
    float m = 0.f;
    for (; i + 3 * S < n4; i += 4 * S) {
        float4 v0 = x4[i], v1 = x4[i + S], v2 = x4[i + 2 * S], v3 = x4[i + 3 * S];
        m = fmaxf(m, fmaxf(fmaxf(fabsf(v0.x), fabsf(v0.y)), fmaxf(fabsf(v0.z), fabsf(v0.w))));
        m = fmaxf(m, fmaxf(fmaxf(fabsf(v1.x), fabsf(v1.y)), fmaxf(fabsf(v1.z), fabsf(v1.w))));
        m = fmaxf(m, fmaxf(fmaxf(fabsf(v2.x), fabsf(v2.y)), fmaxf(fabsf(v2.z), fabsf(v2.w))));
        m = fmaxf(m, fmaxf(fmaxf(fabsf(v3.x), fabsf(v3.y)), fmaxf(fabsf(v3.z), fabsf(v3.w))));
    }
    for (; i < n4; i += S) {
        float4 v = x4[i];
        m = fmaxf(m, fmaxf(fmaxf(fabsf(v.x), fabsf(v.y)), fmaxf(fabsf(v.z), fabsf(v.w))));
    }
    #pragma unroll
    for (int off = 32; off > 0; off >>= 1) m = fmaxf(m, __shfl_xor(m, off, 64));
    if ((threadIdx.x & 63) == 0) atomicMax(out, __float_as_uint(m));
}

// ---------------- scale finalize ----------------
__global__ void k_scale(const float* __restrict__ clip, const unsigned int* __restrict__ maxbits,
                        float* __restrict__ s_out) {
    float m = __uint_as_float(*maxbits);
    float sig = 1.f / (1.f + expf(-clip[0]));
    float s = sig * m / 127.f;
    s_out[0] = s;
    s_out[1] = 1.f / s;
}

// ---------------- quantize fp32 -> packed int8 (16 elems/thread/iter) ----------------
__global__ void k_quant_f32_i8(const float* __restrict__ in, int4* __restrict__ out,
                               const float* __restrict__ sptr, size_t n16) {
    float r = sptr[1];
    size_t S = (size_t)gridDim.x * blockDim.x;
    size_t i = (size_t)blockIdx.x * blockDim.x + threadIdx.x;
    const float4* in4 = (const float4*)in;
    for (; i < n16; i += S) {
        float4 v0 = in4[4 * i], v1 = in4[4 * i + 1], v2 = in4[4 * i + 2], v3 = in4[4 * i + 3];
        int4 o;
        o.x = pack4(v0, r); o.y = pack4(v1, r); o.z = pack4(v2, r); o.w = pack4(v3, r);
        out[i] = o;
    }
}

// ---------------- per-row weight quantization ----------------
__global__ void k_quant_w_i8(const float* __restrict__ W, int8_t* __restrict__ Q,
                             float* __restrict__ srow, int cols) {
    int row = blockIdx.x;
    const float* w = W + (size_t)row * cols;
    float m = 0.f;
    for (int c = threadIdx.x; c < cols; c += 256) m = fmaxf(m, fabsf(w[c]));
    #pragma unroll
    for (int off = 32; off > 0; off >>= 1) m = fmaxf(m, __shfl_xor(m, off, 64));
    __shared__ float red[4];
    if ((threadIdx.x & 63) == 0) red[threadIdx.x >> 6] = m;
    __syncthreads();
    if (threadIdx.x == 0) {
        float mm = fmaxf(fmaxf(red[0], red[1]), fmaxf(red[2], red[3]));
        red[0] = mm / 127.f;
        srow[row] = mm / 127.f;
    }
    __syncthreads();
    float s = red[0];
    for (int c = threadIdx.x; c < cols; c += 256)
        Q[(size_t)row * cols + c] = (int8_t)q1div(w[c], s);
}

// ================= GEMM1 fused (gate+up), i8 MFMA =================
// Tile 256(M) x 128(N each of g,u), BK=64, 512 thr (8 waves 2Mx4N), wave 128x32(g)+128x32(u).
// 2-buffer LDS 64 KB -> 2 blocks/CU (two independent barrier groups).
// One barrier per K-tile; staging issued ~800cy before its vmcnt(0).
__global__ __launch_bounds__(512, 4) void k_gemm1_i8(
    const int8_t* __restrict__ Aq, const int8_t* __restrict__ Bg, const int8_t* __restrict__ Bu,
    const float* __restrict__ sg, const float* __restrict__ su, const float* __restrict__ sx,
    float* __restrict__ Hout, unsigned int* __restrict__ maxh)
{
    constexpr int K = 1024, N = 2816, NT = K / 64, TB = 32768;
    __shared__ int8_t lds[2 * TB];   // per buffer: A[256][64] 16K | Bg[128][64] 8K | Bu[128][64] 8K

    const int ntn = N / 128;                         // 22
    // XCD-chunked bijective swizzle (grid = 5632 = 8*704)
    const int chunk = gridDim.x >> 3;
    const int wg = ((int)blockIdx.x & 7) * chunk + ((int)blockIdx.x >> 3);
    const int mt = wg / ntn, nt = wg % ntn;
    const int m0 = mt * 256, n0 = nt * 128;
    const int tid = threadIdx.x;
    const int wid = tid >> 6, lane = tid & 63;
    const int wm = wid >> 2, wn = wid & 3;
    const int lr = lane & 15, lk = lane >> 4;

    // staging: linear LDS dest, inverse-swizzled global source (rule #21)
    const int srow = tid >> 2;                       // 0..127
    const int scol = ((tid & 3) ^ ((srow >> 1) & 3)) << 4;
    const int8_t* gA0 = Aq + (size_t)(m0 + srow) * K + scol;
    const int8_t* gA1 = gA0 + (size_t)128 * K;
    const int8_t* gG  = Bg + (size_t)(n0 + srow) * K + scol;
    const int8_t* gU  = Bu + (size_t)(n0 + srow) * K + scol;
    const int ldst = wid << 10;                      // wave-uniform 1 KB chunk within each 8 KB region

    // fragment read offsets (swizzled) — layout verified round 1
    const int swz = (lk ^ ((lr >> 1) & 3)) << 4;
    int offA[8], offG[2], offU[2];
    #pragma unroll
    for (int mi = 0; mi < 8; ++mi) offA[mi] = (wm * 128 + mi * 16 + lr) * 64 + swz;
    #pragma unroll
    for (int ni = 0; ni < 2; ++ni) {
        offG[ni] = 16384 + (wn * 32 + ni * 16 + lr) * 64 + swz;
        offU[ni] = 24576 + (wn * 32 + ni * 16 + lr) * 64 + swz;
    }

    i32x4 accg[8][2] = {};
    i32x4 accu[8][2] = {};

    auto stage = [&](int t, int b) {
        const size_t k0 = (size_t)t * 64;
        int8_t* L = &lds[b * TB];
        GLD16(gA0 + k0, L + ldst);
        GLD16(gA1 + k0, L + 8192  + ldst);
        GLD16(gG  + k0, L + 16384 + ldst);
        GLD16(gU  + k0, L + 24576 + ldst);
    };

    stage(0, 0);
    asm volatile("s_waitcnt vmcnt(0)" ::: "memory");
    BARRIER();                                       // tile 0 ready for all waves

    for (int t = 0; t < NT; ++t) {
        // issue next tile's staging FIRST (max in-flight time). Target buffer's last
        // readers finished before the barrier that ended tile t-1.
        if (t + 1 < NT) stage(t + 1, (t + 1) & 1);

        const int8_t* L = &lds[(t & 1) * TB];
        i32x4 a[8], bgf[2], buf_[2];
        #pragma unroll
        for (int ni = 0; ni < 2; ++ni) {
            bgf[ni]  = *(const i32x4*)(L + offG[ni]);
            buf_[ni] = *(const i32x4*)(L + offU[ni]);
        }
        #pragma unroll
        for (int mi = 0; mi < 8; ++mi) a[mi] = *(const i32x4*)(L + offA[mi]);

        __builtin_amdgcn_s_setprio(1);
        #pragma unroll
        for (int mi = 0; mi < 8; ++mi) {
            #pragma unroll
            for (int ni = 0; ni < 2; ++ni) {
                accg[mi][ni] = __builtin_amdgcn_mfma_i32_16x16x64_i8(a[mi], bgf[ni], accg[mi][ni], 0, 0, 0);
                accu[mi][ni] = __builtin_amdgcn_mfma_i32_16x16x64_i8(a[mi], buf_[ni], accu[mi][ni], 0, 0, 0);
            }
        }
        __builtin_amdgcn_s_setprio(0);

        // my 4 stage-loads for tile t+1 (issued ~800cy ago) must land; then block-wide sync:
        // after this barrier every wave's staging landed AND buf[t&1] is free for reuse.
        asm volatile("s_waitcnt vmcnt(0)" ::: "memory");
        BARRIER();
    }

    // epilogue: SwiGLU + h write + global max
    const float s_x = sx[0];
    float lmax = 0.f;
    #pragma unroll
    for (int ni = 0; ni < 2; ++ni) {
        const int n = n0 + wn * 32 + ni * 16 + lr;
        const float fg = s_x * sg[n];
        const float fu = s_x * su[n];
        #pragma unroll
        for (int mi = 0; mi < 8; ++mi) {
            const int mb = m0 + wm * 128 + mi * 16 + lk * 4;
            #pragma unroll
            for (int r = 0; r < 4; ++r) {
                float g = (float)accg[mi][ni][r] * fg;
                float u = (float)accu[mi][ni][r] * fu;
                float h = g * u / (1.f + expf(-g));
                Hout[(size_t)(mb + r) * N + n] = h;
                lmax = fmaxf(lmax, fabsf(h));
            }
        }
    }
    #pragma unroll
    for (int off = 32; off > 0; off >>= 1) lmax = fmaxf(lmax, __shfl_xor(lmax, off, 64));
    if (lane == 0) atomicMax(maxh, __float_as_uint(lmax));
}

// ================= GEMM2: out = (q_h @ q_wd^T) * s_h * s_wd[n], same schedule =================
// Tile 256x256, BK=64, 512 thr (8 waves 2Mx4N), wave 128x64. 2-buffer 64 KB -> 2 blocks/CU.
__global__ __launch_bounds__(512, 4) void k_gemm2_i8(
    const int8_t* __restrict__ Aq, const int8_t* __restrict__ Bw,
    const float* __restrict__ sw, const float* __restrict__ sh,
    float* __restrict__ Out)
{
    constexpr int K = 2816, N = 1024, NT = K / 64, TB = 32768;
    __shared__ int8_t lds[2 * TB];   // per buffer: A[256][64] 16K | B[256][64] 16K

    // XCD-chunked bijective swizzle (grid = 1024 = 8*128)
    const int chunk = gridDim.x >> 3;
    const int wg = ((int)blockIdx.x & 7) * chunk + ((int)blockIdx.x >> 3);
    const int mt = wg >> 2, nt = wg & 3;             // ntn = 1024/256 = 4
    const int m0 = mt * 256, n0 = nt * 256;
    const int tid = threadIdx.x;
    const int wid = tid >> 6, lane = tid & 63;
    const int wm = wid >> 2, wn = wid & 3;
    const int lr = lane & 15, lk = lane >> 4;

    const int srow = tid >> 2;                       // 0..127
    const int scol = ((tid & 3) ^ ((srow >> 1) & 3)) << 4;
    const int8_t* gA0 = Aq + (size_t)(m0 + srow) * K + scol;
    const int8_t* gA1 = gA0 + (size_t)128 * K;
    const int8_t* gB0 = Bw + (size_t)(n0 + srow) * K + scol;
    const int8_t* gB1 = gB0 + (size_t)128 * K;
    const int ldst = wid << 10;

    const int swz = (lk ^ ((lr >> 1) & 3)) << 4;
    int offA[8], offB[4];
    #pragma unroll
    for (int mi = 0; mi < 8; ++mi) offA[mi] = (wm * 128 + mi * 16 + lr) * 64 + swz;
    #pragma unroll
    for (int ni = 0; ni < 4; ++ni) offB[ni] = 16384 + (wn * 64 + ni * 16 + lr) * 64 + swz;

    i32x4 acc[8][4] = {};

    auto stage = [&](int t, int b) {
        const size_t k0 = (size_t)t * 64;
        int8_t* L = &lds[b * TB];
        GLD16(gA0 + k0, L + ldst);
        GLD16(gA1 + k0, L + 8192  + ldst);
        GLD16(gB0 + k0, L + 16384 + ldst);
        GLD16(gB1 + k0, L + 24576 + ldst);
    };

    stage(0, 0);
    asm volatile("s_waitcnt vmcnt(0)" ::: "memory");
    BARRIER();

    for (int t = 0; t < NT; ++t) {
        if (t + 1 < NT) stage(t + 1, (t + 1) & 1);

        const int8_t* L = &lds[(t & 1) * TB];
        i32x4 a[8], b[4];
        #pragma unroll
        for (int ni = 0; ni < 4; ++ni) b[ni] = *(const i32x4*)(L + offB[ni]);
        #pragma unroll
        for (int mi = 0; mi < 8; ++mi) a[mi] = *(const i32x4*)(L + offA[mi]);

        __builtin_amdgcn_s_setprio(1);
        #pragma unroll
        for (int mi = 0; mi < 8; ++mi) {
            #pragma unroll
            for (int ni = 0; ni < 4; ++ni)
                acc[mi][ni] = __builtin_amdgcn_mfma_i32_16x16x64_i8(a[mi], b[ni], acc[mi][ni], 0, 0, 0);
        }
        __builtin_amdgcn_s_setprio(0);

        asm volatile("s_waitcnt vmcnt(0)" ::: "memory");
        BARRIER();
    }

    const float s_h = sh[0];
    #pragma unroll
    for (int ni = 0; ni < 4; ++ni) {
        const int n = n0 + wn * 64 + ni * 16 + lr;
        const float f = s_h * sw[n];
        #pragma unroll
        for (int mi = 0; mi < 8; ++mi) {
            const int mb = m0 + wm * 128 + mi * 16 + lk * 4;
            #pragma unroll
            for (int r = 0; r < 4; ++r)
                Out[(size_t)(mb + r) * N + n] = (float)acc[mi][ni][r] * f;
        }
    }
}

extern "C" void kernel_launch(void* const* d_in, const int* in_sizes, int n_in,
                              void* d_out, int out_size, void* d_ws, size_t ws_size,
                              hipStream_t stream) {
    const float* x       = (const float*)d_in[0];
    const float* clip_x  = (const float*)d_in[1];
    const float* clip_dn = (const float*)d_in[2];
    const float* w_gate  = (const float*)d_in[3];
    const float* w_up    = (const float*)d_in[4];
    const float* w_down  = (const float*)d_in[5];
    float* out = (float*)d_out;

    const int Hd = 1024, Id = 2816;
    const int M = in_sizes[0] / Hd;                  // 65536
    const size_t nx = (size_t)M * Hd;
    const size_t nh = (size_t)M * Id;

    char* ws = (char*)d_ws;
    size_t off = 0;
    auto alloc = [&](size_t bytes) -> char* {
        char* p = ws + off;
        off = (off + bytes + 255) & ~(size_t)255;
        return p;
    };
    unsigned int* max_slots = (unsigned int*)alloc(8);   // [0]=max|x|, [1]=max|h|
    float* sxp = (float*)alloc(8);                       // [0]=scale, [1]=1/scale
    float* shp = (float*)alloc(8);
    int8_t* qx  = (int8_t*)alloc(nx);
    int8_t* qwg = (int8_t*)alloc((size_t)Id * Hd);
    int8_t* qwu = (int8_t*)alloc((size_t)Id * Hd);
    int8_t* qwd = (int8_t*)alloc((size_t)Hd * Id);
    float* swg = (float*)alloc((size_t)Id * 4);
    float* swu = (float*)alloc((size_t)Id * 4);
    float* swd = (float*)alloc((size_t)Hd * 4);
    int8_t* qh = (int8_t*)alloc(nh);
    float* hbuf = (float*)alloc(nh * 4);

    hipMemsetAsync(max_slots, 0, 8, stream);

    k_absmax<<<4096, 256, 0, stream>>>(x, nx / 4, &max_slots[0]);
    k_scale<<<1, 1, 0, stream>>>(clip_x, &max_slots[0], sxp);
    k_quant_f32_i8<<<2048, 256, 0, stream>>>(x, (int4*)qx, sxp, nx / 16);
    k_quant_w_i8<<<Id, 256, 0, stream>>>(w_gate, qwg, swg, Hd);
    k_quant_w_i8<<<Id, 256, 0, stream>>>(w_up, qwu, swu, Hd);
    k_quant_w_i8<<<Hd, 256, 0, stream>>>(w_down, qwd, swd, Id);

    k_gemm1_i8<<<(M / 256) * (Id / 128), 512, 0, stream>>>(qx, qwg, qwu, swg, swu, sxp,
                                                           hbuf, &max_slots[1]);
    k_scale<<<1, 1, 0, stream>>>(clip_dn, &max_slots[1], shp);
    k_quant_f32_i8<<<4096, 256, 0, stream>>>(hbuf, (int4*)qh, shp, nh / 16);

    k_gemm2_i8<<<(M / 256) * (Hd / 256), 512, 0, stream>>>(qh, qwd, swd, shp, out);
}

// Round 5
// 1554.365 us; speedup vs baseline: 3.8302x; 3.8302x over previous
//
#include <hip/hip_runtime.h>
#include <stdint.h>

typedef __attribute__((ext_vector_type(4))) int i32x4;

typedef const __attribute__((address_space(1))) void gvoid_t;
typedef __attribute__((address_space(3))) void lvoid_t;

#define GLD16(g, l) __builtin_amdgcn_global_load_lds((gvoid_t*)(g), (lvoid_t*)(l), 16, 0, 0)
#define SCHEDB() __builtin_amdgcn_sched_barrier(0)

__device__ inline int q1mul(float x, float r) {
    return (int)fminf(fmaxf(rintf(x * r), -128.f), 127.f);
}
__device__ inline int q1div(float x, float s) {
    return (int)fminf(fmaxf(rintf(x / s), -128.f), 127.f);
}
__device__ inline int pack4(float4 v, float r) {
    return (q1mul(v.x, r) & 255) | ((q1mul(v.y, r) & 255) << 8) |
           ((q1mul(v.z, r) & 255) << 16) | ((q1mul(v.w, r) & 255) << 24);
}

// ---------------- global absmax ----------------
__global__ void k_absmax(const float* __restrict__ x, size_t n4, unsigned int* __restrict__ out) {
    size_t S = (size_t)gridDim.x * blockDim.x;
    size_t i = (size_t)blockIdx.x * blockDim.x + threadIdx.x;
    const float4* x4 = (const float4*)x;
    float m = 0.f;
    for (; i + 3 * S < n4; i += 4 * S) {
        float4 v0 = x4[i], v1 = x4[i + S], v2 = x4[i + 2 * S], v3 = x4[i + 3 * S];
        m = fmaxf(m, fmaxf(fmaxf(fabsf(v0.x), fabsf(v0.y)), fmaxf(fabsf(v0.z), fabsf(v0.w))));
        m = fmaxf(m, fmaxf(fmaxf(fabsf(v1.x), fabsf(v1.y)), fmaxf(fabsf(v1.z), fabsf(v1.w))));
        m = fmaxf(m, fmaxf(fmaxf(fabsf(v2.x), fabsf(v2.y)), fmaxf(fabsf(v2.z), fabsf(v2.w))));
        m = fmaxf(m, fmaxf(fmaxf(fabsf(v3.x), fabsf(v3.y)), fmaxf(fabsf(v3.z), fabsf(v3.w))));
    }
    for (; i < n4; i += S) {
        float4 v = x4[i];
        m = fmaxf(m, fmaxf(fmaxf(fabsf(v.x), fabsf(v.y)), fmaxf(fabsf(v.z), fabsf(v.w))));
    }
    #pragma unroll
    for (int off = 32; off > 0; off >>= 1) m = fmaxf(m, __shfl_xor(m, off, 64));
    if ((threadIdx.x & 63) == 0) atomicMax(out, __float_as_uint(m));
}

// ---------------- scale finalize ----------------
__global__ void k_scale(const float* __restrict__ clip, const unsigned int* __restrict__ maxbits,
                        float* __restrict__ s_out) {
    float m = __uint_as_float(*maxbits);
    float sig = 1.f / (1.f + expf(-clip[0]));
    float s = sig * m / 127.f;
    s_out[0] = s;
    s_out[1] = 1.f / s;
}

// ---------------- quantize fp32 -> packed int8 (16 elems/thread/iter) ----------------
__global__ void k_quant_f32_i8(const float* __restrict__ in, int4* __restrict__ out,
                               const float* __restrict__ sptr, size_t n16) {
    float r = sptr[1];
    size_t S = (size_t)gridDim.x * blockDim.x;
    size_t i = (size_t)blockIdx.x * blockDim.x + threadIdx.x;
    const float4* in4 = (const float4*)in;
    for (; i < n16; i += S) {
        float4 v0 = in4[4 * i], v1 = in4[4 * i + 1], v2 = in4[4 * i + 2], v3 = in4[4 * i + 3];
        int4 o;
        o.x = pack4(v0, r); o.y = pack4(v1, r); o.z = pack4(v2, r); o.w = pack4(v3, r);
        out[i] = o;
    }
}

// ---------------- per-row weight quantization ----------------
__global__ void k_quant_w_i8(const float* __restrict__ W, int8_t* __restrict__ Q,
                             float* __restrict__ srow, int cols) {
    int row = blockIdx.x;
    const float* w = W + (size_t)row * cols;
    float m = 0.f;
    for (int c = threadIdx.x; c < cols; c += 256) m = fmaxf(m, fabsf(w[c]));
    #pragma unroll
    for (int off = 32; off > 0; off >>= 1) m = fmaxf(m, __shfl_xor(m, off, 64));
    __shared__ float red[4];
    if ((threadIdx.x & 63) == 0) red[threadIdx.x >> 6] = m;
    __syncthreads();
    if (threadIdx.x == 0) {
        float mm = fmaxf(fmaxf(red[0], red[1]), fmaxf(red[2], red[3]));
        red[0] = mm / 127.f;
        srow[row] = mm / 127.f;
    }
    __syncthreads();
    float s = red[0];
    for (int c = threadIdx.x; c < cols; c += 256)
        Q[(size_t)row * cols + c] = (int8_t)q1div(w[c], s);
}

// ================= GEMM1 fused (gate+up), i8 MFMA =================
// Tile 256(M) x 128(N each of g,u), BK=64, 512 thr (8 waves 2Mx4N), wave 128x32(g)+128x32(u).
// A: LDS double-buffer (16 KB/buf). B(g,u): global->VGPR, register double-buffered 1 tile ahead.
// One barrier + one counted vmcnt(4) per K-tile.
__global__ __launch_bounds__(512, 2) void k_gemm1_i8(
    const int8_t* __restrict__ Aq, const int8_t* __restrict__ Bg, const int8_t* __restrict__ Bu,
    const float* __restrict__ sg, const float* __restrict__ su, const float* __restrict__ sx,
    float* __restrict__ Hout, unsigned int* __restrict__ maxh)
{
    constexpr int K = 1024, N = 2816, NT = K / 64, TB = 16384;
    __shared__ int8_t lds[2 * TB];   // A only: [256 rows][64 B] per buffer

    const int ntn = N / 128;                         // 22
    // XCD-chunked bijective swizzle (grid = 5632 = 8*704)
    const int chunk = gridDim.x >> 3;
    const int wg = ((int)blockIdx.x & 7) * chunk + ((int)blockIdx.x >> 3);
    const int mt = wg / ntn, nt = wg % ntn;
    const int m0 = mt * 256, n0 = nt * 128;
    const int tid = threadIdx.x;
    const int wid = tid >> 6, lane = tid & 63;
    const int wm = wid >> 2, wn = wid & 3;
    const int lr = lane & 15, lk = lane >> 4;

    // A staging: linear LDS dest, inverse-swizzled global source (rule #21)
    const int srow = tid >> 2;                       // 0..127
    const int scol = ((tid & 3) ^ ((srow >> 1) & 3)) << 4;
    const int8_t* gA0 = Aq + (size_t)(m0 + srow) * K + scol;
    const int8_t* gA1 = gA0 + (size_t)128 * K;
    const int ldst = wid << 10;                      // wave-uniform 1 KB chunk

    // A fragment read offsets (swizzled; net effect = linear chunk lk of row)
    const int swz = (lk ^ ((lr >> 1) & 3)) << 4;
    int offA[8];
    #pragma unroll
    for (int mi = 0; mi < 8; ++mi) offA[mi] = (wm * 128 + mi * 16 + lr) * 64 + swz;

    // B per-lane global bases: row n = n0 + wn*32 + ni*16 + lr, bytes t*64 + lk*16
    const int8_t* gGl = Bg + (size_t)(n0 + wn * 32 + lr) * K + lk * 16;
    const int8_t* gUl = Bu + (size_t)(n0 + wn * 32 + lr) * K + lk * 16;

    i32x4 accg[8][2] = {};
    i32x4 accu[8][2] = {};
    i32x4 bgA[2], buA[2], bgB[2], buB[2];            // even/odd B register sets

    // prologue: stage A(0), load B(0) into set A
    GLD16(gA0, &lds[0] + ldst);
    GLD16(gA1, &lds[0] + 8192 + ldst);
    SCHEDB();
    bgA[0] = *(const i32x4*)(gGl);
    bgA[1] = *(const i32x4*)(gGl + (size_t)16 * K);
    buA[0] = *(const i32x4*)(gUl);
    buA[1] = *(const i32x4*)(gUl + (size_t)16 * K);
    SCHEDB();
    asm volatile("s_waitcnt vmcnt(4)\n\ts_barrier" ::: "memory");   // A(0) landed; B(0) in flight

#define G1_STEP(T, CG, CU, NG, NU)                                              \
    {                                                                           \
        const int t_ = (T);                                                     \
        const bool st_ = (t_ + 1 < NT);                                         \
        if (st_) {                                                              \
            const size_t k1 = (size_t)(t_ + 1) * 64;                            \
            int8_t* Ls = &lds[((t_ + 1) & 1) * TB];                             \
            GLD16(gA0 + k1, Ls + ldst);                                         \
            GLD16(gA1 + k1, Ls + 8192 + ldst);                                  \
            SCHEDB();                                                           \
            NG[0] = *(const i32x4*)(gGl + k1);                                  \
            NG[1] = *(const i32x4*)(gGl + (size_t)16 * K + k1);                 \
            NU[0] = *(const i32x4*)(gUl + k1);                                  \
            NU[1] = *(const i32x4*)(gUl + (size_t)16 * K + k1);                 \
            SCHEDB();                                                           \
        }                                                                       \
        const int8_t* L = &lds[(t_ & 1) * TB];                                  \
        i32x4 a_[8];                                                            \
        _Pragma("unroll")                                                       \
        for (int mi = 0; mi < 8; ++mi) a_[mi] = *(const i32x4*)(L + offA[mi]);  \
        __builtin_amdgcn_s_setprio(1);                                          \
        _Pragma("unroll")                                                       \
        for (int mi = 0; mi < 8; ++mi) {                                        \
            _Pragma("unroll")                                                   \
            for (int ni = 0; ni < 2; ++ni) {                                    \
                accg[mi][ni] = __builtin_amdgcn_mfma_i32_16x16x64_i8(a_[mi], CG[ni], accg[mi][ni], 0, 0, 0); \
                accu[mi][ni] = __builtin_amdgcn_mfma_i32_16x16x64_i8(a_[mi], CU[ni], accu[mi][ni], 0, 0, 0); \
            }                                                                   \
        }                                                                       \
        __builtin_amdgcn_s_setprio(0);                                          \
        if (st_) { asm volatile("s_waitcnt vmcnt(4)\n\ts_barrier" ::: "memory"); } \
        else     { asm volatile("s_waitcnt vmcnt(0)\n\ts_barrier" ::: "memory"); } \
    }

    for (int t = 0; t < NT; t += 2) {
        G1_STEP(t,     bgA, buA, bgB, buB);
        G1_STEP(t + 1, bgB, buB, bgA, buA);
    }
#undef G1_STEP

    // epilogue: SwiGLU + h write + global max (layout verified round 1)
    const float s_x = sx[0];
    float lmax = 0.f;
    #pragma unroll
    for (int ni = 0; ni < 2; ++ni) {
        const int n = n0 + wn * 32 + ni * 16 + lr;
        const float fg = s_x * sg[n];
        const float fu = s_x * su[n];
        #pragma unroll
        for (int mi = 0; mi < 8; ++mi) {
            const int mb = m0 + wm * 128 + mi * 16 + lk * 4;
            #pragma unroll
            for (int r = 0; r < 4; ++r) {
                float g = (float)accg[mi][ni][r] * fg;
                float u = (float)accu[mi][ni][r] * fu;
                float h = g * u / (1.f + expf(-g));
                Hout[(size_t)(mb + r) * N + n] = h;
                lmax = fmaxf(lmax, fabsf(h));
            }
        }
    }
    #pragma unroll
    for (int off = 32; off > 0; off >>= 1) lmax = fmaxf(lmax, __shfl_xor(lmax, off, 64));
    if (lane == 0) atomicMax(maxh, __float_as_uint(lmax));
}

// ================= GEMM2: out = (q_h @ q_wd^T) * s_h * s_wd[n] =================
// Tile 256x256, BK=64, 512 thr (8 waves 2Mx4N), wave 128x64.
// A: LDS double-buffer; B: global->VGPR register double-buffer (w_down quantized = 2.75 MB, L2-resident).
__global__ __launch_bounds__(512, 2) void k_gemm2_i8(
    const int8_t* __restrict__ Aq, const int8_t* __restrict__ Bw,
    const float* __restrict__ sw, const float* __restrict__ sh,
    float* __restrict__ Out)
{
    constexpr int K = 2816, N = 1024, NT = K / 64, TB = 16384;
    __shared__ int8_t lds[2 * TB];   // A only

    // XCD-chunked bijective swizzle (grid = 1024 = 8*128)
    const int chunk = gridDim.x >> 3;
    const int wg = ((int)blockIdx.x & 7) * chunk + ((int)blockIdx.x >> 3);
    const int mt = wg >> 2, nt = wg & 3;             // nt fast: B panel hot in L2
    const int m0 = mt * 256, n0 = nt * 256;
    const int tid = threadIdx.x;
    const int wid = tid >> 6, lane = tid & 63;
    const int wm = wid >> 2, wn = wid & 3;
    const int lr = lane & 15, lk = lane >> 4;

    const int srow = tid >> 2;                       // 0..127
    const int scol = ((tid & 3) ^ ((srow >> 1) & 3)) << 4;
    const int8_t* gA0 = Aq + (size_t)(m0 + srow) * K + scol;
    const int8_t* gA1 = gA0 + (size_t)128 * K;
    const int ldst = wid << 10;

    const int swz = (lk ^ ((lr >> 1) & 3)) << 4;
    int offA[8];
    #pragma unroll
    for (int mi = 0; mi < 8; ++mi) offA[mi] = (wm * 128 + mi * 16 + lr) * 64 + swz;

    // B per-lane global base: row n = n0 + wn*64 + ni*16 + lr
    const int8_t* gBl = Bw + (size_t)(n0 + wn * 64 + lr) * K + lk * 16;

    i32x4 acc[8][4] = {};
    i32x4 bA[4], bB[4];

    GLD16(gA0, &lds[0] + ldst);
    GLD16(gA1, &lds[0] + 8192 + ldst);
    SCHEDB();
    #pragma unroll
    for (int ni = 0; ni < 4; ++ni) bA[ni] = *(const i32x4*)(gBl + (size_t)(16 * ni) * K);
    SCHEDB();
    asm volatile("s_waitcnt vmcnt(4)\n\ts_barrier" ::: "memory");

#define G2_STEP(T, CB, NB)                                                      \
    {                                                                           \
        const int t_ = (T);                                                     \
        const bool st_ = (t_ + 1 < NT);                                         \
        if (st_) {                                                              \
            const size_t k1 = (size_t)(t_ + 1) * 64;                            \
            int8_t* Ls = &lds[((t_ + 1) & 1) * TB];                             \
            GLD16(gA0 + k1, Ls + ldst);                                         \
            GLD16(gA1 + k1, Ls + 8192 + ldst);                                  \
            SCHEDB();                                                           \
            _Pragma("unroll")                                                   \
            for (int ni = 0; ni < 4; ++ni)                                      \
                NB[ni] = *(const i32x4*)(gBl + (size_t)(16 * ni) * K + k1);     \
            SCHEDB();                                                           \
        }                                                                       \
        const int8_t* L = &lds[(t_ & 1) * TB];                                  \
        i32x4 a_[8];                                                            \
        _Pragma("unroll")                                                       \
        for (int mi = 0; mi < 8; ++mi) a_[mi] = *(const i32x4*)(L + offA[mi]);  \
        __builtin_amdgcn_s_setprio(1);                                          \
        _Pragma("unroll")                                                       \
        for (int mi = 0; mi < 8; ++mi) {                                        \
            _Pragma("unroll")                                                   \
            for (int ni = 0; ni < 4; ++ni)                                      \
                acc[mi][ni] = __builtin_amdgcn_mfma_i32_16x16x64_i8(a_[mi], CB[ni], acc[mi][ni], 0, 0, 0); \
        }                                                                       \
        __builtin_amdgcn_s_setprio(0);                                          \
        if (st_) { asm volatile("s_waitcnt vmcnt(4)\n\ts_barrier" ::: "memory"); } \
        else     { asm volatile("s_waitcnt vmcnt(0)\n\ts_barrier" ::: "memory"); } \
    }

    for (int t = 0; t < NT; t += 2) {
        G2_STEP(t,     bA, bB);
        G2_STEP(t + 1, bB, bA);
    }
#undef G2_STEP

    const float s_h = sh[0];
    #pragma unroll
    for (int ni = 0; ni < 4; ++ni) {
        const int n = n0 + wn * 64 + ni * 16 + lr;
        const float f = s_h * sw[n];
        #pragma unroll
        for (int mi = 0; mi < 8; ++mi) {
            const int mb = m0 + wm * 128 + mi * 16 + lk * 4;
            #pragma unroll
            for (int r = 0; r < 4; ++r)
                Out[(size_t)(mb + r) * N + n] = (float)acc[mi][ni][r] * f;
        }
    }
}

extern "C" void kernel_launch(void* const* d_in, const int* in_sizes, int n_in,
                              void* d_out, int out_size, void* d_ws, size_t ws_size,
                              hipStream_t stream) {
    const float* x       = (const float*)d_in[0];
    const float* clip_x  = (const float*)d_in[1];
    const float* clip_dn = (const float*)d_in[2];
    const float* w_gate  = (const float*)d_in[3];
    const float* w_up    = (const float*)d_in[4];
    const float* w_down  = (const float*)d_in[5];
    float* out = (float*)d_out;

    const int Hd = 1024, Id = 2816;
    const int M = in_sizes[0] / Hd;                  // 65536
    const size_t nx = (size_t)M * Hd;
    const size_t nh = (size_t)M * Id;

    char* ws = (char*)d_ws;
    size_t off = 0;
    auto alloc = [&](size_t bytes) -> char* {
        char* p = ws + off;
        off = (off + bytes + 255) & ~(size_t)255;
        return p;
    };
    unsigned int* max_slots = (unsigned int*)alloc(8);   // [0]=max|x|, [1]=max|h|
    float* sxp = (float*)alloc(8);                       // [0]=scale, [1]=1/scale
    float* shp = (float*)alloc(8);
    int8_t* qx  = (int8_t*)alloc(nx);
    int8_t* qwg = (int8_t*)alloc((size_t)Id * Hd);
    int8_t* qwu = (int8_t*)alloc((size_t)Id * Hd);
    int8_t* qwd = (int8_t*)alloc((size_t)Hd * Id);
    float* swg = (float*)alloc((size_t)Id * 4);
    float* swu = (float*)alloc((size_t)Id * 4);
    float* swd = (float*)alloc((size_t)Hd * 4);
    int8_t* qh = (int8_t*)alloc(nh);
    float* hbuf = (float*)alloc(nh * 4);

    hipMemsetAsync(max_slots, 0, 8, stream);

    k_absmax<<<4096, 256, 0, stream>>>(x, nx / 4, &max_slots[0]);
    k_scale<<<1, 1, 0, stream>>>(clip_x, &max_slots[0], sxp);
    k_quant_f32_i8<<<2048, 256, 0, stream>>>(x, (int4*)qx, sxp, nx / 16);
    k_quant_w_i8<<<Id, 256, 0, stream>>>(w_gate, qwg, swg, Hd);
    k_quant_w_i8<<<Id, 256, 0, stream>>>(w_up, qwu, swu, Hd);
    k_quant_w_i8<<<Hd, 256, 0, stream>>>(w_down, qwd, swd, Id);

    k_gemm1_i8<<<(M / 256) * (Id / 128), 512, 0, stream>>>(qx, qwg, qwu, swg, swu, sxp,
                                                           hbuf, &max_slots[1]);
    k_scale<<<1, 1, 0, stream>>>(clip_dn, &max_slots[1], shp);
    k_quant_f32_i8<<<4096, 256, 0, stream>>>(hbuf, (int4*)qh, shp, nh / 16);

    k_gemm2_i8<<<(M / 256) * (Hd / 256), 512, 0, stream>>>(qh, qwd, swd, shp, out);
}

// Round 6
// 1372.185 us; speedup vs baseline: 4.3387x; 1.1328x over previous
//
#include <hip/hip_runtime.h>
#include <stdint.h>

typedef __attribute__((ext_vector_type(4))) int i32x4;

typedef const __attribute__((address_space(1))) void gvoid_t;
typedef __attribute__((address_space(3))) void lvoid_t;

#define GLD16(g, l) __builtin_amdgcn_global_load_lds((gvoid_t*)(g), (lvoid_t*)(l), 16, 0, 0)
#define FENCE() asm volatile("" ::: "memory")
#define BARRIER() do { FENCE(); __builtin_amdgcn_s_barrier(); FENCE(); } while (0)
#define VMCNT4() asm volatile("s_waitcnt vmcnt(4)" ::: "memory")
#define VMCNT0() asm volatile("s_waitcnt vmcnt(0)" ::: "memory")

__device__ inline int q1mul(float x, float r) {
    return (int)fminf(fmaxf(rintf(x * r), -128.f), 127.f);
}
__device__ inline int q1div(float x, float s) {
    return (int)fminf(fmaxf(rintf(x / s), -128.f), 127.f);
}
__device__ inline int pack4(float4 v, float r) {
    return (q1mul(v.x, r) & 255) | ((q1mul(v.y, r) & 255) << 8) |
           ((q1mul(v.z, r) & 255) << 16) | ((q1mul(v.w, r) & 255) << 24);
}

// ---------------- global absmax ----------------
__global__ void k_absmax(const float* __restrict__ x, size_t n4, unsigned int* __restrict__ out) {
    size_t S = (size_t)gridDim.x * blockDim.x;
    size_t i = (size_t)blockIdx.x * blockDim.x + threadIdx.x;
    const float4* x4 = (const float4*)x;
    float m = 0.f;
    for (; i + 3 * S < n4; i += 4 * S) {
        float4 v0 = x4[i], v1 = x4[i + S], v2 = x4[i + 2 * S], v3 = x4[i + 3 * S];
        m = fmaxf(m, fmaxf(fmaxf(fabsf(v0.x), fabsf(v0.y)), fmaxf(fabsf(v0.z), fabsf(v0.w))));
        m = fmaxf(m, fmaxf(fmaxf(fabsf(v1.x), fabsf(v1.y)), fmaxf(fabsf(v1.z), fabsf(v1.w))));
        m = fmaxf(m, fmaxf(fmaxf(fabsf(v2.x), fabsf(v2.y)), fmaxf(fabsf(v2.z), fabsf(v2.w))));
        m = fmaxf(m, fmaxf(fmaxf(fabsf(v3.x), fabsf(v3.y)), fmaxf(fabsf(v3.z), fabsf(v3.w))));
    }
    for (; i < n4; i += S) {
        float4 v = x4[i];
        m = fmaxf(m, fmaxf(fmaxf(fabsf(v.x), fabsf(v.y)), fmaxf(fabsf(v.z), fabsf(v.w))));
    }
    #pragma unroll
    for (int off = 32; off > 0; off >>= 1) m = fmaxf(m, __shfl_xor(m, off, 64));
    if ((threadIdx.x & 63) == 0) atomicMax(out, __float_as_uint(m));
}

// ---------------- scale finalize ----------------
__global__ void k_scale(const float* __restrict__ clip, const unsigned int* __restrict__ maxbits,
                        float* __restrict__ s_out) {
    float m = __uint_as_float(*maxbits);
    float sig = 1.f / (1.f + expf(-clip[0]));
    float s = sig * m / 127.f;
    s_out[0] = s;
    s_out[1] = 1.f / s;
}

// ---------------- quantize fp32 -> packed int8 ----------------
__global__ void k_quant_f32_i8(const float* __restrict__ in, int4* __restrict__ out,
                               const float* __restrict__ sptr, size_t n16) {
    float r = sptr[1];
    size_t S = (size_t)gridDim.x * blockDim.x;
    size_t i = (size_t)blockIdx.x * blockDim.x + threadIdx.x;
    const float4* in4 = (const float4*)in;
    for (; i < n16; i += S) {
        float4 v0 = in4[4 * i], v1 = in4[4 * i + 1], v2 = in4[4 * i + 2], v3 = in4[4 * i + 3];
        int4 o;
        o.x = pack4(v0, r); o.y = pack4(v1, r); o.z = pack4(v2, r); o.w = pack4(v3, r);
        out[i] = o;
    }
}

// ---------------- per-row weight quantization ----------------
__global__ void k_quant_w_i8(const float* __restrict__ W, int8_t* __restrict__ Q,
                             float* __restrict__ srow, int cols) {
    int row = blockIdx.x;
    const float* w = W + (size_t)row * cols;
    float m = 0.f;
    for (int c = threadIdx.x; c < cols; c += 256) m = fmaxf(m, fabsf(w[c]));
    #pragma unroll
    for (int off = 32; off > 0; off >>= 1) m = fmaxf(m, __shfl_xor(m, off, 64));
    __shared__ float red[4];
    if ((threadIdx.x & 63) == 0) red[threadIdx.x >> 6] = m;
    __syncthreads();
    if (threadIdx.x == 0) {
        float mm = fmaxf(fmaxf(red[0], red[1]), fmaxf(red[2], red[3]));
        red[0] = mm / 127.f;
        srow[row] = mm / 127.f;
    }
    __syncthreads();
    float s = red[0];
    for (int c = threadIdx.x; c < cols; c += 256)
        Q[(size_t)row * cols + c] = (int8_t)q1div(w[c], s);
}

// ================= GEMM1 fused (gate+up) — m201 8-phase template, i8-isomorphic =================
// Tile 256(M) x 128(N each of g,u), BK=128 B (two 64 B k-slabs), 512 thr (8 waves 2Mx4N).
// LDS/buf 64 KB: A0@0 A1@16K G0@32K U0@40K G1@48K U1@56K. 2 buffers = 128 KB.
// Per K-tile 4 phases (ks,mh); stage order A0,G0U0,A1,G1U1; counted vmcnt(4) at end of p2 & p4.
__global__ __launch_bounds__(512, 2) void k_gemm1_i8(
    const int8_t* __restrict__ Aq, const int8_t* __restrict__ Bg, const int8_t* __restrict__ Bu,
    const float* __restrict__ sg, const float* __restrict__ su, const float* __restrict__ sx,
    float* __restrict__ Hout, unsigned int* __restrict__ maxh)
{
    constexpr int K = 1024, N = 2816, NT = K / 128, BUF = 65536;
    __shared__ int8_t lds[2 * BUF];

    const int ntn = N / 128;                         // 22
    const int chunk = gridDim.x >> 3;                // grid = 5632 = 8*704
    const int wg = ((int)blockIdx.x & 7) * chunk + ((int)blockIdx.x >> 3);
    const int mt = wg / ntn, nt = wg % ntn;
    const int m0 = mt * 256, n0 = nt * 128;
    const int tid = threadIdx.x;
    const int wid = tid >> 6, lane = tid & 63;
    const int wm = wid >> 2, wn = wid & 3;
    const int lr = lane & 15, lk = lane >> 4;

    // staging: linear LDS dest, inverse-swizzled global source (rule #21), per 64B-row slab
    const int srow = tid >> 2;                       // 0..127
    const int scol = ((tid & 3) ^ ((srow >> 1) & 3)) << 4;
    const int8_t* gA0 = Aq + (size_t)(m0 + srow) * K + scol;
    const int8_t* gA1 = gA0 + (size_t)128 * K;
    const int8_t* gG  = Bg + (size_t)(n0 + srow) * K + scol;
    const int8_t* gU  = Bu + (size_t)(n0 + srow) * K + scol;
    const int ldst = wid << 10;

    // fragment read offsets within a slab (verified round 1)
    const int swz = (lk ^ ((lr >> 1) & 3)) << 4;

    i32x4 accg[8][2] = {};
    i32x4 accu[8][2] = {};

    // prologue: stage tile 0, order A0,G0U0,A1,G1U1
    {
        int8_t* Lw = &lds[0];
        GLD16(gA0,      Lw + ldst);         GLD16(gA1,      Lw + 8192  + ldst);
        GLD16(gG,       Lw + 32768 + ldst); GLD16(gU,       Lw + 40960 + ldst);
        GLD16(gA0 + 64, Lw + 16384 + ldst); GLD16(gA1 + 64, Lw + 24576 + ldst);
        GLD16(gG  + 64, Lw + 49152 + ldst); GLD16(gU  + 64, Lw + 57344 + ldst);
    }
    VMCNT4();            // A0,G0,U0 of tile 0 landed; A1,G1,U1 in flight
    BARRIER();

    for (int t = 0; t < NT; ++t) {
        const bool st = (t + 1 < NT);
        const size_t kk = (size_t)(t + 1) * 128;
        const int8_t* Lr = &lds[(t & 1) * BUF];
        int8_t* Lw = &lds[((t + 1) & 1) * BUF];
        i32x4 a[4], bg[2], bu[2];

        // ---- p1: ks0, mh0 — read A0[mh0] + G0/U0; stage A0(t+1) ----
        #pragma unroll
        for (int mi = 0; mi < 4; ++mi)
            a[mi] = *(const i32x4*)(Lr + (wm * 128 + mi * 16 + lr) * 64 + swz);
        #pragma unroll
        for (int ni = 0; ni < 2; ++ni) {
            bg[ni] = *(const i32x4*)(Lr + 32768 + (wn * 32 + ni * 16 + lr) * 64 + swz);
            bu[ni] = *(const i32x4*)(Lr + 40960 + (wn * 32 + ni * 16 + lr) * 64 + swz);
        }
        if (st) { GLD16(gA0 + kk, Lw + ldst); GLD16(gA1 + kk, Lw + 8192 + ldst); }
        BARRIER();
        __builtin_amdgcn_s_setprio(1);
        #pragma unroll
        for (int mi = 0; mi < 4; ++mi)
            #pragma unroll
            for (int ni = 0; ni < 2; ++ni) {
                accg[mi][ni] = __builtin_amdgcn_mfma_i32_16x16x64_i8(a[mi], bg[ni], accg[mi][ni], 0, 0, 0);
                accu[mi][ni] = __builtin_amdgcn_mfma_i32_16x16x64_i8(a[mi], bu[ni], accu[mi][ni], 0, 0, 0);
            }
        __builtin_amdgcn_s_setprio(0);
        BARRIER();

        // ---- p2: ks0, mh1 — read A0[mh1]; stage G0U0(t+1); gate for p3 data ----
        #pragma unroll
        for (int mi = 0; mi < 4; ++mi)
            a[mi] = *(const i32x4*)(Lr + (wm * 128 + 64 + mi * 16 + lr) * 64 + swz);
        if (st) { GLD16(gG + kk, Lw + 32768 + ldst); GLD16(gU + kk, Lw + 40960 + ldst); }
        BARRIER();
        __builtin_amdgcn_s_setprio(1);
        #pragma unroll
        for (int mi = 0; mi < 4; ++mi)
            #pragma unroll
            for (int ni = 0; ni < 2; ++ni) {
                accg[4 + mi][ni] = __builtin_amdgcn_mfma_i32_16x16x64_i8(a[mi], bg[ni], accg[4 + mi][ni], 0, 0, 0);
                accu[4 + mi][ni] = __builtin_amdgcn_mfma_i32_16x16x64_i8(a[mi], bu[ni], accu[4 + mi][ni], 0, 0, 0);
            }
        __builtin_amdgcn_s_setprio(0);
        if (st) { VMCNT4(); } else { VMCNT0(); }    // drain this tile's A1,G1,U1 (issued 1 tile ago)
        BARRIER();

        // ---- p3: ks1, mh0 — read A1[mh0] + G1/U1; stage A1(t+1) ----
        #pragma unroll
        for (int mi = 0; mi < 4; ++mi)
            a[mi] = *(const i32x4*)(Lr + 16384 + (wm * 128 + mi * 16 + lr) * 64 + swz);
        #pragma unroll
        for (int ni = 0; ni < 2; ++ni) {
            bg[ni] = *(const i32x4*)(Lr + 49152 + (wn * 32 + ni * 16 + lr) * 64 + swz);
            bu[ni] = *(const i32x4*)(Lr + 57344 + (wn * 32 + ni * 16 + lr) * 64 + swz);
        }
        if (st) { GLD16(gA0 + kk + 64, Lw + 16384 + ldst); GLD16(gA1 + kk + 64, Lw + 24576 + ldst); }
        BARRIER();
        __builtin_amdgcn_s_setprio(1);
        #pragma unroll
        for (int mi = 0; mi < 4; ++mi)
            #pragma unroll
            for (int ni = 0; ni < 2; ++ni) {
                accg[mi][ni] = __builtin_amdgcn_mfma_i32_16x16x64_i8(a[mi], bg[ni], accg[mi][ni], 0, 0, 0);
                accu[mi][ni] = __builtin_amdgcn_mfma_i32_16x16x64_i8(a[mi], bu[ni], accu[mi][ni], 0, 0, 0);
            }
        __builtin_amdgcn_s_setprio(0);
        BARRIER();

        // ---- p4: ks1, mh1 — read A1[mh1]; stage G1U1(t+1); gate for next tile's p1 ----
        #pragma unroll
        for (int mi = 0; mi < 4; ++mi)
            a[mi] = *(const i32x4*)(Lr + 16384 + (wm * 128 + 64 + mi * 16 + lr) * 64 + swz);
        if (st) { GLD16(gG + kk + 64, Lw + 49152 + ldst); GLD16(gU + kk + 64, Lw + 57344 + ldst); }
        BARRIER();
        __builtin_amdgcn_s_setprio(1);
        #pragma unroll
        for (int mi = 0; mi < 4; ++mi)
            #pragma unroll
            for (int ni = 0; ni < 2; ++ni) {
                accg[4 + mi][ni] = __builtin_amdgcn_mfma_i32_16x16x64_i8(a[mi], bg[ni], accg[4 + mi][ni], 0, 0, 0);
                accu[4 + mi][ni] = __builtin_amdgcn_mfma_i32_16x16x64_i8(a[mi], bu[ni], accu[4 + mi][ni], 0, 0, 0);
            }
        __builtin_amdgcn_s_setprio(0);
        if (st) { VMCNT4(); }                       // next tile's A0,G0,U0 landed
        BARRIER();
    }

    // epilogue: SwiGLU + h write + global max (verified round 1)
    const float s_x = sx[0];
    float lmax = 0.f;
    #pragma unroll
    for (int ni = 0; ni < 2; ++ni) {
        const int n = n0 + wn * 32 + ni * 16 + lr;
        const float fg = s_x * sg[n];
        const float fu = s_x * su[n];
        #pragma unroll
        for (int mi = 0; mi < 8; ++mi) {
            const int mb = m0 + wm * 128 + mi * 16 + lk * 4;
            #pragma unroll
            for (int r = 0; r < 4; ++r) {
                float g = (float)accg[mi][ni][r] * fg;
                float u = (float)accu[mi][ni][r] * fu;
                float h = g * u / (1.f + expf(-g));
                Hout[(size_t)(mb + r) * N + n] = h;
                lmax = fmaxf(lmax, fabsf(h));
            }
        }
    }
    #pragma unroll
    for (int off = 32; off > 0; off >>= 1) lmax = fmaxf(lmax, __shfl_xor(lmax, off, 64));
    if (lane == 0) atomicMax(maxh, __float_as_uint(lmax));
}

// ================= GEMM2 — same 8-phase template, 256x256 =================
// LDS/buf 64 KB: A0@0 A1@16K B0@32K B1@48K(=49152). Stage order A0,B0,A1,B1.
__global__ __launch_bounds__(512, 2) void k_gemm2_i8(
    const int8_t* __restrict__ Aq, const int8_t* __restrict__ Bw,
    const float* __restrict__ sw, const float* __restrict__ sh,
    float* __restrict__ Out)
{
    constexpr int K = 2816, N = 1024, NT = K / 128, BUF = 65536;   // NT = 22
    __shared__ int8_t lds[2 * BUF];

    const int chunk = gridDim.x >> 3;                // grid = 1024 = 8*128
    const int wg = ((int)blockIdx.x & 7) * chunk + ((int)blockIdx.x >> 3);
    const int mt = wg >> 2, nt = wg & 3;
    const int m0 = mt * 256, n0 = nt * 256;
    const int tid = threadIdx.x;
    const int wid = tid >> 6, lane = tid & 63;
    const int wm = wid >> 2, wn = wid & 3;
    const int lr = lane & 15, lk = lane >> 4;

    const int srow = tid >> 2;
    const int scol = ((tid & 3) ^ ((srow >> 1) & 3)) << 4;
    const int8_t* gA0 = Aq + (size_t)(m0 + srow) * K + scol;
    const int8_t* gA1 = gA0 + (size_t)128 * K;
    const int8_t* gB0 = Bw + (size_t)(n0 + srow) * K + scol;
    const int8_t* gB1 = gB0 + (size_t)128 * K;
    const int ldst = wid << 10;

    const int swz = (lk ^ ((lr >> 1) & 3)) << 4;

    i32x4 acc[8][4] = {};

    {
        int8_t* Lw = &lds[0];
        GLD16(gA0,      Lw + ldst);         GLD16(gA1,      Lw + 8192  + ldst);
        GLD16(gB0,      Lw + 32768 + ldst); GLD16(gB1,      Lw + 40960 + ldst);
        GLD16(gA0 + 64, Lw + 16384 + ldst); GLD16(gA1 + 64, Lw + 24576 + ldst);
        GLD16(gB0 + 64, Lw + 49152 + ldst); GLD16(gB1 + 64, Lw + 57344 + ldst);
    }
    VMCNT4();
    BARRIER();

    for (int t = 0; t < NT; ++t) {
        const bool st = (t + 1 < NT);
        const size_t kk = (size_t)(t + 1) * 128;
        const int8_t* Lr = &lds[(t & 1) * BUF];
        int8_t* Lw = &lds[((t + 1) & 1) * BUF];
        i32x4 a[4], b[4];

        // ---- p1: ks0, mh0 ----
        #pragma unroll
        for (int mi = 0; mi < 4; ++mi)
            a[mi] = *(const i32x4*)(Lr + (wm * 128 + mi * 16 + lr) * 64 + swz);
        #pragma unroll
        for (int ni = 0; ni < 4; ++ni)
            b[ni] = *(const i32x4*)(Lr + 32768 + (wn * 64 + ni * 16 + lr) * 64 + swz);
        if (st) { GLD16(gA0 + kk, Lw + ldst); GLD16(gA1 + kk, Lw + 8192 + ldst); }
        BARRIER();
        __builtin_amdgcn_s_setprio(1);
        #pragma unroll
        for (int mi = 0; mi < 4; ++mi)
            #pragma unroll
            for (int ni = 0; ni < 4; ++ni)
                acc[mi][ni] = __builtin_amdgcn_mfma_i32_16x16x64_i8(a[mi], b[ni], acc[mi][ni], 0, 0, 0);
        __builtin_amdgcn_s_setprio(0);
        BARRIER();

        // ---- p2: ks0, mh1 ----
        #pragma unroll
        for (int mi = 0; mi < 4; ++mi)
            a[mi] = *(const i32x4*)(Lr + (wm * 128 + 64 + mi * 16 + lr) * 64 + swz);
        if (st) { GLD16(gB0 + kk, Lw + 32768 + ldst); GLD16(gB1 + kk, Lw + 40960 + ldst); }
        BARRIER();
        __builtin_amdgcn_s_setprio(1);
        #pragma unroll
        for (int mi = 0; mi < 4; ++mi)
            #pragma unroll
            for (int ni = 0; ni < 4; ++ni)
                acc[4 + mi][ni] = __builtin_amdgcn_mfma_i32_16x16x64_i8(a[mi], b[ni], acc[4 + mi][ni], 0, 0, 0);
        __builtin_amdgcn_s_setprio(0);
        if (st) { VMCNT4(); } else { VMCNT0(); }
        BARRIER();

        // ---- p3: ks1, mh0 ----
        #pragma unroll
        for (int mi = 0; mi < 4; ++mi)
            a[mi] = *(const i32x4*)(Lr + 16384 + (wm * 128 + mi * 16 + lr) * 64 + swz);
        #pragma unroll
        for (int ni = 0; ni < 4; ++ni)
            b[ni] = *(const i32x4*)(Lr + 49152 + (wn * 64 + ni * 16 + lr) * 64 + swz);
        if (st) { GLD16(gA0 + kk + 64, Lw + 16384 + ldst); GLD16(gA1 + kk + 64, Lw + 24576 + ldst); }
        BARRIER();
        __builtin_amdgcn_s_setprio(1);
        #pragma unroll
        for (int mi = 0; mi < 4; ++mi)
            #pragma unroll
            for (int ni = 0; ni < 4; ++ni)
                acc[mi][ni] = __builtin_amdgcn_mfma_i32_16x16x64_i8(a[mi], b[ni], acc[mi][ni], 0, 0, 0);
        __builtin_amdgcn_s_setprio(0);
        BARRIER();

        // ---- p4: ks1, mh1 ----
        #pragma unroll
        for (int mi = 0; mi < 4; ++mi)
            a[mi] = *(const i32x4*)(Lr + 16384 + (wm * 128 + 64 + mi * 16 + lr) * 64 + swz);
        if (st) { GLD16(gB0 + kk + 64, Lw + 49152 + ldst); GLD16(gB1 + kk + 64, Lw + 57344 + ldst); }
        BARRIER();
        __builtin_amdgcn_s_setprio(1);
        #pragma unroll
        for (int mi = 0; mi < 4; ++mi)
            #pragma unroll
            for (int ni = 0; ni < 4; ++ni)
                acc[4 + mi][ni] = __builtin_amdgcn_mfma_i32_16x16x64_i8(a[mi], b[ni], acc[4 + mi][ni], 0, 0, 0);
        __builtin_amdgcn_s_setprio(0);
        if (st) { VMCNT4(); }
        BARRIER();
    }

    const float s_h = sh[0];
    #pragma unroll
    for (int ni = 0; ni < 4; ++ni) {
        const int n = n0 + wn * 64 + ni * 16 + lr;
        const float f = s_h * sw[n];
        #pragma unroll
        for (int mi = 0; mi < 8; ++mi) {
            const int mb = m0 + wm * 128 + mi * 16 + lk * 4;
            #pragma unroll
            for (int r = 0; r < 4; ++r)
                Out[(size_t)(mb + r) * N + n] = (float)acc[mi][ni][r] * f;
        }
    }
}

extern "C" void kernel_launch(void* const* d_in, const int* in_sizes, int n_in,
                              void* d_out, int out_size, void* d_ws, size_t ws_size,
                              hipStream_t stream) {
    const float* x       = (const float*)d_in[0];
    const float* clip_x  = (const float*)d_in[1];
    const float* clip_dn = (const float*)d_in[2];
    const float* w_gate  = (const float*)d_in[3];
    const float* w_up    = (const float*)d_in[4];
    const float* w_down  = (const float*)d_in[5];
    float* out = (float*)d_out;

    const int Hd = 1024, Id = 2816;
    const int M = in_sizes[0] / Hd;                  // 65536
    const size_t nx = (size_t)M * Hd;
    const size_t nh = (size_t)M * Id;

    char* ws = (char*)d_ws;
    size_t off = 0;
    auto alloc = [&](size_t bytes) -> char* {
        char* p = ws + off;
        off = (off + bytes + 255) & ~(size_t)255;
        return p;
    };
    unsigned int* max_slots = (unsigned int*)alloc(8);   // [0]=max|x|, [1]=max|h|
    float* sxp = (float*)alloc(8);                       // [0]=scale, [1]=1/scale
    float* shp = (float*)alloc(8);
    int8_t* qx  = (int8_t*)alloc(nx);
    int8_t* qwg = (int8_t*)alloc((size_t)Id * Hd);
    int8_t* qwu = (int8_t*)alloc((size_t)Id * Hd);
    int8_t* qwd = (int8_t*)alloc((size_t)Hd * Id);
    float* swg = (float*)alloc((size_t)Id * 4);
    float* swu = (float*)alloc((size_t)Id * 4);
    float* swd = (float*)alloc((size_t)Hd * 4);
    int8_t* qh = (int8_t*)alloc(nh);
    float* hbuf = (float*)alloc(nh * 4);

    hipMemsetAsync(max_slots, 0, 8, stream);

    k_absmax<<<4096, 256, 0, stream>>>(x, nx / 4, &max_slots[0]);
    k_scale<<<1, 1, 0, stream>>>(clip_x, &max_slots[0], sxp);
    k_quant_f32_i8<<<2048, 256, 0, stream>>>(x, (int4*)qx, sxp, nx / 16);
    k_quant_w_i8<<<Id, 256, 0, stream>>>(w_gate, qwg, swg, Hd);
    k_quant_w_i8<<<Id, 256, 0, stream>>>(w_up, qwu, swu, Hd);
    k_quant_w_i8<<<Hd, 256, 0, stream>>>(w_down, qwd, swd, Id);

    k_gemm1_i8<<<(M / 256) * (Id / 128), 512, 0, stream>>>(qx, qwg, qwu, swg, swu, sxp,
                                                           hbuf, &max_slots[1]);
    k_scale<<<1, 1, 0, stream>>>(clip_dn, &max_slots[1], shp);
    k_quant_f32_i8<<<4096, 256, 0, stream>>>(hbuf, (int4*)qh, shp, nh / 16);

    k_gemm2_i8<<<(M / 256) * (Hd / 256), 512, 0, stream>>>(qh, qwd, swd, shp, out);
}

// Round 7
// 1257.546 us; speedup vs baseline: 4.7343x; 1.0912x over previous
//
#include <hip/hip_runtime.h>
#include <stdint.h>

typedef __attribute__((ext_vector_type(4))) int i32x4;

typedef const __attribute__((address_space(1))) void gvoid_t;
typedef __attribute__((address_space(3))) void lvoid_t;

#define GLD16(g, l) __builtin_amdgcn_global_load_lds((gvoid_t*)(g), (lvoid_t*)(l), 16, 0, 0)
#define FENCE() asm volatile("" ::: "memory")
#define BARRIER() do { FENCE(); __builtin_amdgcn_s_barrier(); FENCE(); } while (0)
#define VMCNT4() asm volatile("s_waitcnt vmcnt(4)" ::: "memory")
#define VMCNT0() asm volatile("s_waitcnt vmcnt(0)" ::: "memory")

__device__ inline int q1mul(float x, float r) {
    return (int)fminf(fmaxf(rintf(x * r), -128.f), 127.f);
}
__device__ inline int q1div(float x, float s) {
    return (int)fminf(fmaxf(rintf(x / s), -128.f), 127.f);
}
__device__ inline int pack4(float4 v, float r) {
    return (q1mul(v.x, r) & 255) | ((q1mul(v.y, r) & 255) << 8) |
           ((q1mul(v.z, r) & 255) << 16) | ((q1mul(v.w, r) & 255) << 24);
}

// ---------------- global absmax ----------------
__global__ void k_absmax(const float* __restrict__ x, size_t n4, unsigned int* __restrict__ out) {
    size_t S = (size_t)gridDim.x * blockDim.x;
    size_t i = (size_t)blockIdx.x * blockDim.x + threadIdx.x;
    const float4* x4 = (const float4*)x;
    float m = 0.f;
    for (; i + 3 * S < n4; i += 4 * S) {
        float4 v0 = x4[i], v1 = x4[i + S], v2 = x4[i + 2 * S], v3 = x4[i + 3 * S];
        m = fmaxf(m, fmaxf(fmaxf(fabsf(v0.x), fabsf(v0.y)), fmaxf(fabsf(v0.z), fabsf(v0.w))));
        m = fmaxf(m, fmaxf(fmaxf(fabsf(v1.x), fabsf(v1.y)), fmaxf(fabsf(v1.z), fabsf(v1.w))));
        m = fmaxf(m, fmaxf(fmaxf(fabsf(v2.x), fabsf(v2.y)), fmaxf(fabsf(v2.z), fabsf(v2.w))));
        m = fmaxf(m, fmaxf(fmaxf(fabsf(v3.x), fabsf(v3.y)), fmaxf(fabsf(v3.z), fabsf(v3.w))));
    }
    for (; i < n4; i += S) {
        float4 v = x4[i];
        m = fmaxf(m, fmaxf(fmaxf(fabsf(v.x), fabsf(v.y)), fmaxf(fabsf(v.z), fabsf(v.w))));
    }
    #pragma unroll
    for (int off = 32; off > 0; off >>= 1) m = fmaxf(m, __shfl_xor(m, off, 64));
    if ((threadIdx.x & 63) == 0) atomicMax(out, __float_as_uint(m));
}

// ---------------- scale finalize ----------------
__global__ void k_scale(const float* __restrict__ clip, const unsigned int* __restrict__ maxbits,
                        float* __restrict__ s_out) {
    float m = __uint_as_float(*maxbits);
    float sig = 1.f / (1.f + expf(-clip[0]));
    float s = sig * m / 127.f;
    s_out[0] = s;
    s_out[1] = 1.f / s;
}

// ---------------- quantize fp32 -> packed int8 ----------------
__global__ void k_quant_f32_i8(const float* __restrict__ in, int4* __restrict__ out,
                               const float* __restrict__ sptr, size_t n16) {
    float r = sptr[1];
    size_t S = (size_t)gridDim.x * blockDim.x;
    size_t i = (size_t)blockIdx.x * blockDim.x + threadIdx.x;
    const float4* in4 = (const float4*)in;
    for (; i < n16; i += S) {
        float4 v0 = in4[4 * i], v1 = in4[4 * i + 1], v2 = in4[4 * i + 2], v3 = in4[4 * i + 3];
        int4 o;
        o.x = pack4(v0, r); o.y = pack4(v1, r); o.z = pack4(v2, r); o.w = pack4(v3, r);
        out[i] = o;
    }
}

// ---------------- quantize h16 (per-block scale) -> packed int8 ----------------
// h16[M,2816]; block key = (row>>8)*22 + (col>>7); h = h16 * sblk[key]/32766
__global__ void k_quant_h16_i8(const short* __restrict__ h16, const float* __restrict__ sblk,
                               const float* __restrict__ sh, int4* __restrict__ qh, size_t nchunks) {
    const float rh = sh[1] * (1.f / 32766.f);
    size_t S = (size_t)gridDim.x * blockDim.x;
    size_t i = (size_t)blockIdx.x * blockDim.x + threadIdx.x;
    for (; i < nchunks; i += S) {                       // 16 h16 per chunk; 176 chunks/row
        int row = (int)(i / 176);
        int col = (int)(i - (size_t)row * 176) * 16;
        float f = sblk[(row >> 8) * 22 + (col >> 7)] * rh;
        const int4* p = (const int4*)(h16 + (size_t)row * 2816 + col);
        int4 lo = p[0], hi = p[1];
        int w[8] = {lo.x, lo.y, lo.z, lo.w, hi.x, hi.y, hi.z, hi.w};
        int ob[4];
        #pragma unroll
        for (int j = 0; j < 4; ++j) {
            int q0 = q1mul((float)(short)(w[2 * j] & 0xFFFF), f);
            int q1 = q1mul((float)(short)(w[2 * j] >> 16), f);
            int q2 = q1mul((float)(short)(w[2 * j + 1] & 0xFFFF), f);
            int q3 = q1mul((float)(short)(w[2 * j + 1] >> 16), f);
            ob[j] = (q0 & 255) | ((q1 & 255) << 8) | ((q2 & 255) << 16) | ((q3 & 255) << 24);
        }
        int4 o; o.x = ob[0]; o.y = ob[1]; o.z = ob[2]; o.w = ob[3];
        qh[i] = o;
    }
}

// ---------------- per-row weight quantization ----------------
__global__ void k_quant_w_i8(const float* __restrict__ W, int8_t* __restrict__ Q,
                             float* __restrict__ srow, int cols) {
    int row = blockIdx.x;
    const float* w = W + (size_t)row * cols;
    float m = 0.f;
    for (int c = threadIdx.x; c < cols; c += 256) m = fmaxf(m, fabsf(w[c]));
    #pragma unroll
    for (int off = 32; off > 0; off >>= 1) m = fmaxf(m, __shfl_xor(m, off, 64));
    __shared__ float red[4];
    if ((threadIdx.x & 63) == 0) red[threadIdx.x >> 6] = m;
    __syncthreads();
    if (threadIdx.x == 0) {
        float mm = fmaxf(fmaxf(red[0], red[1]), fmaxf(red[2], red[3]));
        red[0] = mm / 127.f;
        srow[row] = mm / 127.f;
    }
    __syncthreads();
    float s = red[0];
    for (int c = threadIdx.x; c < cols; c += 256)
        Q[(size_t)row * cols + c] = (int8_t)q1div(w[c], s);
}

// ================= GEMM1 fused (gate+up) — 8-phase structure + nt-split for L2 fit =================
// Launched twice with nt_base = 0, 11. Grid = (M/256)*11 per launch; per-XCD mt-major ordering:
// 11 consecutive blocks share one A panel (256 KB); B-half (2.75 MB) stays L2-resident.
// Epilogue: two-pass h->int16 with per-block scale (exact f32 max feeds global s_h atomic).
__global__ __launch_bounds__(512, 2) void k_gemm1_i8(
    const int8_t* __restrict__ Aq, const int8_t* __restrict__ Bg, const int8_t* __restrict__ Bu,
    const float* __restrict__ sg, const float* __restrict__ su, const float* __restrict__ sx,
    short* __restrict__ H16, float* __restrict__ sblk, unsigned int* __restrict__ maxh,
    int nt_base)
{
    constexpr int K = 1024, N = 2816, NT = K / 128, BUF = 65536;
    __shared__ int8_t lds[2 * BUF];

    // per-XCD mt-major: xcd = bid&7 owns mt range [xcd*mtspan, ...); inner order (mtL, ntL)
    const int wgl = (int)blockIdx.x >> 3;
    const int xcd = (int)blockIdx.x & 7;
    const int mtspan = (int)(gridDim.x >> 3) / 11;
    const int mt = xcd * mtspan + wgl / 11;
    const int nt = nt_base + wgl % 11;
    const int m0 = mt * 256, n0 = nt * 128;
    const int tid = threadIdx.x;
    const int wid = tid >> 6, lane = tid & 63;
    const int wm = wid >> 2, wn = wid & 3;
    const int lr = lane & 15, lk = lane >> 4;

    const int srow = tid >> 2;
    const int scol = ((tid & 3) ^ ((srow >> 1) & 3)) << 4;
    const int8_t* gA0 = Aq + (size_t)(m0 + srow) * K + scol;
    const int8_t* gA1 = gA0 + (size_t)128 * K;
    const int8_t* gG  = Bg + (size_t)(n0 + srow) * K + scol;
    const int8_t* gU  = Bu + (size_t)(n0 + srow) * K + scol;
    const int ldst = wid << 10;

    const int swz = (lk ^ ((lr >> 1) & 3)) << 4;

    i32x4 accg[8][2] = {};
    i32x4 accu[8][2] = {};

    {
        int8_t* Lw = &lds[0];
        GLD16(gA0,      Lw + ldst);         GLD16(gA1,      Lw + 8192  + ldst);
        GLD16(gG,       Lw + 32768 + ldst); GLD16(gU,       Lw + 40960 + ldst);
        GLD16(gA0 + 64, Lw + 16384 + ldst); GLD16(gA1 + 64, Lw + 24576 + ldst);
        GLD16(gG  + 64, Lw + 49152 + ldst); GLD16(gU  + 64, Lw + 57344 + ldst);
    }
    VMCNT4();
    BARRIER();

    for (int t = 0; t < NT; ++t) {
        const bool st = (t + 1 < NT);
        const size_t kk = (size_t)(t + 1) * 128;
        const int8_t* Lr = &lds[(t & 1) * BUF];
        int8_t* Lw = &lds[((t + 1) & 1) * BUF];
        i32x4 a[4], bg[2], bu[2];

        // ---- p1 ----
        #pragma unroll
        for (int mi = 0; mi < 4; ++mi)
            a[mi] = *(const i32x4*)(Lr + (wm * 128 + mi * 16 + lr) * 64 + swz);
        #pragma unroll
        for (int ni = 0; ni < 2; ++ni) {
            bg[ni] = *(const i32x4*)(Lr + 32768 + (wn * 32 + ni * 16 + lr) * 64 + swz);
            bu[ni] = *(const i32x4*)(Lr + 40960 + (wn * 32 + ni * 16 + lr) * 64 + swz);
        }
        if (st) { GLD16(gA0 + kk, Lw + ldst); GLD16(gA1 + kk, Lw + 8192 + ldst); }
        BARRIER();
        __builtin_amdgcn_s_setprio(1);
        #pragma unroll
        for (int mi = 0; mi < 4; ++mi)
            #pragma unroll
            for (int ni = 0; ni < 2; ++ni) {
                accg[mi][ni] = __builtin_amdgcn_mfma_i32_16x16x64_i8(a[mi], bg[ni], accg[mi][ni], 0, 0, 0);
                accu[mi][ni] = __builtin_amdgcn_mfma_i32_16x16x64_i8(a[mi], bu[ni], accu[mi][ni], 0, 0, 0);
            }
        __builtin_amdgcn_s_setprio(0);
        BARRIER();

        // ---- p2 ----
        #pragma unroll
        for (int mi = 0; mi < 4; ++mi)
            a[mi] = *(const i32x4*)(Lr + (wm * 128 + 64 + mi * 16 + lr) * 64 + swz);
        if (st) { GLD16(gG + kk, Lw + 32768 + ldst); GLD16(gU + kk, Lw + 40960 + ldst); }
        BARRIER();
        __builtin_amdgcn_s_setprio(1);
        #pragma unroll
        for (int mi = 0; mi < 4; ++mi)
            #pragma unroll
            for (int ni = 0; ni < 2; ++ni) {
                accg[4 + mi][ni] = __builtin_amdgcn_mfma_i32_16x16x64_i8(a[mi], bg[ni], accg[4 + mi][ni], 0, 0, 0);
                accu[4 + mi][ni] = __builtin_amdgcn_mfma_i32_16x16x64_i8(a[mi], bu[ni], accu[4 + mi][ni], 0, 0, 0);
            }
        __builtin_amdgcn_s_setprio(0);
        if (st) { VMCNT4(); } else { VMCNT0(); }
        BARRIER();

        // ---- p3 ----
        #pragma unroll
        for (int mi = 0; mi < 4; ++mi)
            a[mi] = *(const i32x4*)(Lr + 16384 + (wm * 128 + mi * 16 + lr) * 64 + swz);
        #pragma unroll
        for (int ni = 0; ni < 2; ++ni) {
            bg[ni] = *(const i32x4*)(Lr + 49152 + (wn * 32 + ni * 16 + lr) * 64 + swz);
            bu[ni] = *(const i32x4*)(Lr + 57344 + (wn * 32 + ni * 16 + lr) * 64 + swz);
        }
        if (st) { GLD16(gA0 + kk + 64, Lw + 16384 + ldst); GLD16(gA1 + kk + 64, Lw + 24576 + ldst); }
        BARRIER();
        __builtin_amdgcn_s_setprio(1);
        #pragma unroll
        for (int mi = 0; mi < 4; ++mi)
            #pragma unroll
            for (int ni = 0; ni < 2; ++ni) {
                accg[mi][ni] = __builtin_amdgcn_mfma_i32_16x16x64_i8(a[mi], bg[ni], accg[mi][ni], 0, 0, 0);
                accu[mi][ni] = __builtin_amdgcn_mfma_i32_16x16x64_i8(a[mi], bu[ni], accu[mi][ni], 0, 0, 0);
            }
        __builtin_amdgcn_s_setprio(0);
        BARRIER();

        // ---- p4 ----
        #pragma unroll
        for (int mi = 0; mi < 4; ++mi)
            a[mi] = *(const i32x4*)(Lr + 16384 + (wm * 128 + 64 + mi * 16 + lr) * 64 + swz);
        if (st) { GLD16(gG + kk + 64, Lw + 49152 + ldst); GLD16(gU + kk + 64, Lw + 57344 + ldst); }
        BARRIER();
        __builtin_amdgcn_s_setprio(1);
        #pragma unroll
        for (int mi = 0; mi < 4; ++mi)
            #pragma unroll
            for (int ni = 0; ni < 2; ++ni) {
                accg[4 + mi][ni] = __builtin_amdgcn_mfma_i32_16x16x64_i8(a[mi], bg[ni], accg[4 + mi][ni], 0, 0, 0);
                accu[4 + mi][ni] = __builtin_amdgcn_mfma_i32_16x16x64_i8(a[mi], bu[ni], accu[4 + mi][ni], 0, 0, 0);
            }
        __builtin_amdgcn_s_setprio(0);
        if (st) { VMCNT4(); }
        BARRIER();
    }

    // ---- epilogue: pass 1 = exact f32 block max; pass 2 = h -> int16 (per-block scale) ----
    const float s_x = sx[0];
    float lmax = 0.f;
    #pragma unroll
    for (int ni = 0; ni < 2; ++ni) {
        const int n = n0 + wn * 32 + ni * 16 + lr;
        const float fg = s_x * sg[n];
        const float fu = s_x * su[n];
        #pragma unroll
        for (int mi = 0; mi < 8; ++mi) {
            #pragma unroll
            for (int r = 0; r < 4; ++r) {
                float g = (float)accg[mi][ni][r] * fg;
                float u = (float)accu[mi][ni][r] * fu;
                float h = g * u / (1.f + expf(-g));
                lmax = fmaxf(lmax, fabsf(h));
            }
        }
    }
    #pragma unroll
    for (int off = 32; off > 0; off >>= 1) lmax = fmaxf(lmax, __shfl_xor(lmax, off, 64));
    float* lred = (float*)lds;                       // K-loop done; LDS free
    if (lane == 0) lred[wid] = lmax;
    BARRIER();
    float bmax = lred[0];
    #pragma unroll
    for (int w = 1; w < 8; ++w) bmax = fmaxf(bmax, lred[w]);
    if (tid == 0) {
        atomicMax(maxh, __float_as_uint(bmax));
        sblk[mt * 22 + nt] = bmax;
    }
    const float qs = 32766.f / fmaxf(bmax, 1e-20f);
    #pragma unroll
    for (int ni = 0; ni < 2; ++ni) {
        const int n = n0 + wn * 32 + ni * 16 + lr;
        const float fg = s_x * sg[n];
        const float fu = s_x * su[n];
        #pragma unroll
        for (int mi = 0; mi < 8; ++mi) {
            const int mb = m0 + wm * 128 + mi * 16 + lk * 4;
            #pragma unroll
            for (int r = 0; r < 4; ++r) {
                float g = (float)accg[mi][ni][r] * fg;
                float u = (float)accu[mi][ni][r] * fu;
                float h = g * u / (1.f + expf(-g));
                H16[(size_t)(mb + r) * N + n] = (short)rintf(h * qs);
            }
        }
    }
}

// ================= GEMM2 — unchanged R6 8-phase structure, 256x256 =================
__global__ __launch_bounds__(512, 2) void k_gemm2_i8(
    const int8_t* __restrict__ Aq, const int8_t* __restrict__ Bw,
    const float* __restrict__ sw, const float* __restrict__ sh,
    float* __restrict__ Out)
{
    constexpr int K = 2816, N = 1024, NT = K / 128, BUF = 65536;   // NT = 22
    __shared__ int8_t lds[2 * BUF];

    const int chunk = gridDim.x >> 3;                // grid = 1024 = 8*128
    const int wg = ((int)blockIdx.x & 7) * chunk + ((int)blockIdx.x >> 3);
    const int mt = wg >> 2, nt = wg & 3;
    const int m0 = mt * 256, n0 = nt * 256;
    const int tid = threadIdx.x;
    const int wid = tid >> 6, lane = tid & 63;
    const int wm = wid >> 2, wn = wid & 3;
    const int lr = lane & 15, lk = lane >> 4;

    const int srow = tid >> 2;
    const int scol = ((tid & 3) ^ ((srow >> 1) & 3)) << 4;
    const int8_t* gA0 = Aq + (size_t)(m0 + srow) * K + scol;
    const int8_t* gA1 = gA0 + (size_t)128 * K;
    const int8_t* gB0 = Bw + (size_t)(n0 + srow) * K + scol;
    const int8_t* gB1 = gB0 + (size_t)128 * K;
    const int ldst = wid << 10;

    const int swz = (lk ^ ((lr >> 1) & 3)) << 4;

    i32x4 acc[8][4] = {};

    {
        int8_t* Lw = &lds[0];
        GLD16(gA0,      Lw + ldst);         GLD16(gA1,      Lw + 8192  + ldst);
        GLD16(gB0,      Lw + 32768 + ldst); GLD16(gB1,      Lw + 40960 + ldst);
        GLD16(gA0 + 64, Lw + 16384 + ldst); GLD16(gA1 + 64, Lw + 24576 + ldst);
        GLD16(gB0 + 64, Lw + 49152 + ldst); GLD16(gB1 + 64, Lw + 57344 + ldst);
    }
    VMCNT4();
    BARRIER();

    for (int t = 0; t < NT; ++t) {
        const bool st = (t + 1 < NT);
        const size_t kk = (size_t)(t + 1) * 128;
        const int8_t* Lr = &lds[(t & 1) * BUF];
        int8_t* Lw = &lds[((t + 1) & 1) * BUF];
        i32x4 a[4], b[4];

        // ---- p1 ----
        #pragma unroll
        for (int mi = 0; mi < 4; ++mi)
            a[mi] = *(const i32x4*)(Lr + (wm * 128 + mi * 16 + lr) * 64 + swz);
        #pragma unroll
        for (int ni = 0; ni < 4; ++ni)
            b[ni] = *(const i32x4*)(Lr + 32768 + (wn * 64 + ni * 16 + lr) * 64 + swz);
        if (st) { GLD16(gA0 + kk, Lw + ldst); GLD16(gA1 + kk, Lw + 8192 + ldst); }
        BARRIER();
        __builtin_amdgcn_s_setprio(1);
        #pragma unroll
        for (int mi = 0; mi < 4; ++mi)
            #pragma unroll
            for (int ni = 0; ni < 4; ++ni)
                acc[mi][ni] = __builtin_amdgcn_mfma_i32_16x16x64_i8(a[mi], b[ni], acc[mi][ni], 0, 0, 0);
        __builtin_amdgcn_s_setprio(0);
        BARRIER();

        // ---- p2 ----
        #pragma unroll
        for (int mi = 0; mi < 4; ++mi)
            a[mi] = *(const i32x4*)(Lr + (wm * 128 + 64 + mi * 16 + lr) * 64 + swz);
        if (st) { GLD16(gB0 + kk, Lw + 32768 + ldst); GLD16(gB1 + kk, Lw + 40960 + ldst); }
        BARRIER();
        __builtin_amdgcn_s_setprio(1);
        #pragma unroll
        for (int mi = 0; mi < 4; ++mi)
            #pragma unroll
            for (int ni = 0; ni < 4; ++ni)
                acc[4 + mi][ni] = __builtin_amdgcn_mfma_i32_16x16x64_i8(a[mi], b[ni], acc[4 + mi][ni], 0, 0, 0);
        __builtin_amdgcn_s_setprio(0);
        if (st) { VMCNT4(); } else { VMCNT0(); }
        BARRIER();

        // ---- p3 ----
        #pragma unroll
        for (int mi = 0; mi < 4; ++mi)
            a[mi] = *(const i32x4*)(Lr + 16384 + (wm * 128 + mi * 16 + lr) * 64 + swz);
        #pragma unroll
        for (int ni = 0; ni < 4; ++ni)
            b[ni] = *(const i32x4*)(Lr + 49152 + (wn * 64 + ni * 16 + lr) * 64 + swz);
        if (st) { GLD16(gA0 + kk + 64, Lw + 16384 + ldst); GLD16(gA1 + kk + 64, Lw + 24576 + ldst); }
        BARRIER();
        __builtin_amdgcn_s_setprio(1);
        #pragma unroll
        for (int mi = 0; mi < 4; ++mi)
            #pragma unroll
            for (int ni = 0; ni < 4; ++ni)
                acc[mi][ni] = __builtin_amdgcn_mfma_i32_16x16x64_i8(a[mi], b[ni], acc[mi][ni], 0, 0, 0);
        __builtin_amdgcn_s_setprio(0);
        BARRIER();

        // ---- p4 ----
        #pragma unroll
        for (int mi = 0; mi < 4; ++mi)
            a[mi] = *(const i32x4*)(Lr + 16384 + (wm * 128 + 64 + mi * 16 + lr) * 64 + swz);
        if (st) { GLD16(gB0 + kk + 64, Lw + 49152 + ldst); GLD16(gB1 + kk + 64, Lw + 57344 + ldst); }
        BARRIER();
        __builtin_amdgcn_s_setprio(1);
        #pragma unroll
        for (int mi = 0; mi < 4; ++mi)
            #pragma unroll
            for (int ni = 0; ni < 4; ++ni)
                acc[4 + mi][ni] = __builtin_amdgcn_mfma_i32_16x16x64_i8(a[mi], b[ni], acc[4 + mi][ni], 0, 0, 0);
        __builtin_amdgcn_s_setprio(0);
        if (st) { VMCNT4(); }
        BARRIER();
    }

    const float s_h = sh[0];
    #pragma unroll
    for (int ni = 0; ni < 4; ++ni) {
        const int n = n0 + wn * 64 + ni * 16 + lr;
        const float f = s_h * sw[n];
        #pragma unroll
        for (int mi = 0; mi < 8; ++mi) {
            const int mb = m0 + wm * 128 + mi * 16 + lk * 4;
            #pragma unroll
            for (int r = 0; r < 4; ++r)
                Out[(size_t)(mb + r) * N + n] = (float)acc[mi][ni][r] * f;
        }
    }
}

extern "C" void kernel_launch(void* const* d_in, const int* in_sizes, int n_in,
                              void* d_out, int out_size, void* d_ws, size_t ws_size,
                              hipStream_t stream) {
    const float* x       = (const float*)d_in[0];
    const float* clip_x  = (const float*)d_in[1];
    const float* clip_dn = (const float*)d_in[2];
    const float* w_gate  = (const float*)d_in[3];
    const float* w_up    = (const float*)d_in[4];
    const float* w_down  = (const float*)d_in[5];
    float* out = (float*)d_out;

    const int Hd = 1024, Id = 2816;
    const int M = in_sizes[0] / Hd;                  // 65536
    const size_t nx = (size_t)M * Hd;
    const size_t nh = (size_t)M * Id;

    char* ws = (char*)d_ws;
    size_t off = 0;
    auto alloc = [&](size_t bytes) -> char* {
        char* p = ws + off;
        off = (off + bytes + 255) & ~(size_t)255;
        return p;
    };
    unsigned int* max_slots = (unsigned int*)alloc(8);   // [0]=max|x|, [1]=max|h|
    float* sxp = (float*)alloc(8);                       // [0]=scale, [1]=1/scale
    float* shp = (float*)alloc(8);
    int8_t* qx  = (int8_t*)alloc(nx);
    int8_t* qwg = (int8_t*)alloc((size_t)Id * Hd);
    int8_t* qwu = (int8_t*)alloc((size_t)Id * Hd);
    int8_t* qwd = (int8_t*)alloc((size_t)Hd * Id);
    float* swg = (float*)alloc((size_t)Id * 4);
    float* swu = (float*)alloc((size_t)Id * 4);
    float* swd = (float*)alloc((size_t)Hd * 4);
    int8_t* qh = (int8_t*)alloc(nh);
    short* h16 = (short*)alloc(nh * 2);
    float* sblk = (float*)alloc((size_t)(M / 256) * 22 * 4);

    hipMemsetAsync(max_slots, 0, 8, stream);

    k_absmax<<<4096, 256, 0, stream>>>(x, nx / 4, &max_slots[0]);
    k_scale<<<1, 1, 0, stream>>>(clip_x, &max_slots[0], sxp);
    k_quant_f32_i8<<<2048, 256, 0, stream>>>(x, (int4*)qx, sxp, nx / 16);
    k_quant_w_i8<<<Id, 256, 0, stream>>>(w_gate, qwg, swg, Hd);
    k_quant_w_i8<<<Id, 256, 0, stream>>>(w_up, qwu, swu, Hd);
    k_quant_w_i8<<<Hd, 256, 0, stream>>>(w_down, qwd, swd, Id);

    const int g1grid = (M / 256) * 11;               // per nt-half
    k_gemm1_i8<<<g1grid, 512, 0, stream>>>(qx, qwg, qwu, swg, swu, sxp, h16, sblk, &max_slots[1], 0);
    k_gemm1_i8<<<g1grid, 512, 0, stream>>>(qx, qwg, qwu, swg, swu, sxp, h16, sblk, &max_slots[1], 11);
    k_scale<<<1, 1, 0, stream>>>(clip_dn, &max_slots[1], shp);
    k_quant_h16_i8<<<4096, 256, 0, stream>>>(h16, sblk, shp, (int4*)qh, nh / 16);

    k_gemm2_i8<<<(M / 256) * (Hd / 256), 512, 0, stream>>>(qh, qwd, swd, shp, out);
}

// Round 8
// 1156.211 us; speedup vs baseline: 5.1492x; 1.0876x over previous
//
#include <hip/hip_runtime.h>
#include <stdint.h>

typedef __attribute__((ext_vector_type(4))) int i32x4;

typedef const __attribute__((address_space(1))) void gvoid_t;
typedef __attribute__((address_space(3))) void lvoid_t;

#define GLD16(g, l) __builtin_amdgcn_global_load_lds((gvoid_t*)(g), (lvoid_t*)(l), 16, 0, 0)
#define FENCE() asm volatile("" ::: "memory")
#define BARRIER() do { FENCE(); __builtin_amdgcn_s_barrier(); FENCE(); } while (0)
#define VMCNT4() asm volatile("s_waitcnt vmcnt(4)" ::: "memory")
#define VMCNT0() asm volatile("s_waitcnt vmcnt(0)" ::: "memory")

__device__ inline int q1mul(float x, float r) {
    return (int)fminf(fmaxf(rintf(x * r), -128.f), 127.f);
}
__device__ inline int q1div(float x, float s) {
    return (int)fminf(fmaxf(rintf(x / s), -128.f), 127.f);
}
__device__ inline int pack4(float4 v, float r) {
    return (q1mul(v.x, r) & 255) | ((q1mul(v.y, r) & 255) << 8) |
           ((q1mul(v.z, r) & 255) << 16) | ((q1mul(v.w, r) & 255) << 24);
}

// ---------------- global absmax (4 independent chains for ILP) ----------------
__global__ void k_absmax(const float* __restrict__ x, size_t n4, unsigned int* __restrict__ out) {
    size_t S = (size_t)gridDim.x * blockDim.x;
    size_t i = (size_t)blockIdx.x * blockDim.x + threadIdx.x;
    const float4* x4 = (const float4*)x;
    float m0 = 0.f, m1 = 0.f, m2 = 0.f, m3 = 0.f;
    for (; i + 3 * S < n4; i += 4 * S) {
        float4 v0 = x4[i], v1 = x4[i + S], v2 = x4[i + 2 * S], v3 = x4[i + 3 * S];
        m0 = fmaxf(m0, fmaxf(fmaxf(fabsf(v0.x), fabsf(v0.y)), fmaxf(fabsf(v0.z), fabsf(v0.w))));
        m1 = fmaxf(m1, fmaxf(fmaxf(fabsf(v1.x), fabsf(v1.y)), fmaxf(fabsf(v1.z), fabsf(v1.w))));
        m2 = fmaxf(m2, fmaxf(fmaxf(fabsf(v2.x), fabsf(v2.y)), fmaxf(fabsf(v2.z), fabsf(v2.w))));
        m3 = fmaxf(m3, fmaxf(fmaxf(fabsf(v3.x), fabsf(v3.y)), fmaxf(fabsf(v3.z), fabsf(v3.w))));
    }
    for (; i < n4; i += S) {
        float4 v = x4[i];
        m0 = fmaxf(m0, fmaxf(fmaxf(fabsf(v.x), fabsf(v.y)), fmaxf(fabsf(v.z), fabsf(v.w))));
    }
    float m = fmaxf(fmaxf(m0, m1), fmaxf(m2, m3));
    #pragma unroll
    for (int off = 32; off > 0; off >>= 1) m = fmaxf(m, __shfl_xor(m, off, 64));
    if ((threadIdx.x & 63) == 0) atomicMax(out, __float_as_uint(m));
}

// ---------------- scale finalize ----------------
__global__ void k_scale(const float* __restrict__ clip, const unsigned int* __restrict__ maxbits,
                        float* __restrict__ s_out) {
    float m = __uint_as_float(*maxbits);
    float sig = 1.f / (1.f + expf(-clip[0]));
    float s = sig * m / 127.f;
    s_out[0] = s;
    s_out[1] = 1.f / s;
}

// ---------------- quantize fp32 -> packed int8 ----------------
__global__ void k_quant_f32_i8(const float* __restrict__ in, int4* __restrict__ out,
                               const float* __restrict__ sptr, size_t n16) {
    float r = sptr[1];
    size_t S = (size_t)gridDim.x * blockDim.x;
    size_t i = (size_t)blockIdx.x * blockDim.x + threadIdx.x;
    const float4* in4 = (const float4*)in;
    for (; i < n16; i += S) {
        float4 v0 = in4[4 * i], v1 = in4[4 * i + 1], v2 = in4[4 * i + 2], v3 = in4[4 * i + 3];
        int4 o;
        o.x = pack4(v0, r); o.y = pack4(v1, r); o.z = pack4(v2, r); o.w = pack4(v3, r);
        out[i] = o;
    }
}

// ---------------- quantize h16 (per-block scale) -> packed int8 ----------------
// h16[M,2816]; block key = (row>>8)*22 + (col>>7); h = h16 * sblk[key]/32766
__global__ void k_quant_h16_i8(const short* __restrict__ h16, const float* __restrict__ sblk,
                               const float* __restrict__ sh, int4* __restrict__ qh, size_t nchunks) {
    const float rh = sh[1] * (1.f / 32766.f);
    size_t S = (size_t)gridDim.x * blockDim.x;
    size_t i = (size_t)blockIdx.x * blockDim.x + threadIdx.x;
    for (; i < nchunks; i += S) {                       // 16 h16 per chunk; 176 chunks/row
        int row = (int)(i / 176);
        int col = (int)(i - (size_t)row * 176) * 16;
        float f = sblk[(row >> 8) * 22 + (col >> 7)] * rh;
        const int4* p = (const int4*)(h16 + (size_t)row * 2816 + col);
        int4 lo = p[0], hi = p[1];
        int w[8] = {lo.x, lo.y, lo.z, lo.w, hi.x, hi.y, hi.z, hi.w};
        int ob[4];
        #pragma unroll
        for (int j = 0; j < 4; ++j) {
            int q0 = q1mul((float)(short)(w[2 * j] & 0xFFFF), f);
            int q1 = q1mul((float)(short)(w[2 * j] >> 16), f);
            int q2 = q1mul((float)(short)(w[2 * j + 1] & 0xFFFF), f);
            int q3 = q1mul((float)(short)(w[2 * j + 1] >> 16), f);
            ob[j] = (q0 & 255) | ((q1 & 255) << 8) | ((q2 & 255) << 16) | ((q3 & 255) << 24);
        }
        int4 o; o.x = ob[0]; o.y = ob[1]; o.z = ob[2]; o.w = ob[3];
        qh[i] = o;
    }
}

// ---------------- per-row weight quantization ----------------
__global__ void k_quant_w_i8(const float* __restrict__ W, int8_t* __restrict__ Q,
                             float* __restrict__ srow, int cols) {
    int row = blockIdx.x;
    const float* w = W + (size_t)row * cols;
    float m = 0.f;
    for (int c = threadIdx.x; c < cols; c += 256) m = fmaxf(m, fabsf(w[c]));
    #pragma unroll
    for (int off = 32; off > 0; off >>= 1) m = fmaxf(m, __shfl_xor(m, off, 64));
    __shared__ float red[4];
    if ((threadIdx.x & 63) == 0) red[threadIdx.x >> 6] = m;
    __syncthreads();
    if (threadIdx.x == 0) {
        float mm = fmaxf(fmaxf(red[0], red[1]), fmaxf(red[2], red[3]));
        red[0] = mm / 127.f;
        srow[row] = mm / 127.f;
    }
    __syncthreads();
    float s = red[0];
    for (int c = threadIdx.x; c < cols; c += 256)
        Q[(size_t)row * cols + c] = (int8_t)q1div(w[c], s);
}

// ================= GEMM1 fused (gate+up) — 8-phase K-loop (R7, unchanged) + LDS-coalesced epilogue =================
// Epilogue: single SwiGLU pass -> f32 h tile in LDS (128 KB exact) -> per-block bmax via sblk atomic
// -> strided LDS read -> int16 quantize -> packed dword coalesced stores (no RMW).
__global__ __launch_bounds__(512, 2) void k_gemm1_i8(
    const int8_t* __restrict__ Aq, const int8_t* __restrict__ Bg, const int8_t* __restrict__ Bu,
    const float* __restrict__ sg, const float* __restrict__ su, const float* __restrict__ sx,
    short* __restrict__ H16, float* __restrict__ sblk, unsigned int* __restrict__ maxh,
    int nt_base)
{
    constexpr int K = 1024, N = 2816, NT = K / 128, BUF = 65536;
    __shared__ int8_t lds[2 * BUF];

    const int wgl = (int)blockIdx.x >> 3;
    const int xcd = (int)blockIdx.x & 7;
    const int mtspan = (int)(gridDim.x >> 3) / 11;
    const int mt = xcd * mtspan + wgl / 11;
    const int nt = nt_base + wgl % 11;
    const int m0 = mt * 256, n0 = nt * 128;
    const int tid = threadIdx.x;
    const int wid = tid >> 6, lane = tid & 63;
    const int wm = wid >> 2, wn = wid & 3;
    const int lr = lane & 15, lk = lane >> 4;

    const int srow = tid >> 2;
    const int scol = ((tid & 3) ^ ((srow >> 1) & 3)) << 4;
    const int8_t* gA0 = Aq + (size_t)(m0 + srow) * K + scol;
    const int8_t* gA1 = gA0 + (size_t)128 * K;
    const int8_t* gG  = Bg + (size_t)(n0 + srow) * K + scol;
    const int8_t* gU  = Bu + (size_t)(n0 + srow) * K + scol;
    const int ldst = wid << 10;

    const int swz = (lk ^ ((lr >> 1) & 3)) << 4;

    i32x4 accg[8][2] = {};
    i32x4 accu[8][2] = {};

    {
        int8_t* Lw = &lds[0];
        GLD16(gA0,      Lw + ldst);         GLD16(gA1,      Lw + 8192  + ldst);
        GLD16(gG,       Lw + 32768 + ldst); GLD16(gU,       Lw + 40960 + ldst);
        GLD16(gA0 + 64, Lw + 16384 + ldst); GLD16(gA1 + 64, Lw + 24576 + ldst);
        GLD16(gG  + 64, Lw + 49152 + ldst); GLD16(gU  + 64, Lw + 57344 + ldst);
    }
    VMCNT4();
    BARRIER();

    for (int t = 0; t < NT; ++t) {
        const bool st = (t + 1 < NT);
        const size_t kk = (size_t)(t + 1) * 128;
        const int8_t* Lr = &lds[(t & 1) * BUF];
        int8_t* Lw = &lds[((t + 1) & 1) * BUF];
        i32x4 a[4], bg[2], bu[2];

        // ---- p1 ----
        #pragma unroll
        for (int mi = 0; mi < 4; ++mi)
            a[mi] = *(const i32x4*)(Lr + (wm * 128 + mi * 16 + lr) * 64 + swz);
        #pragma unroll
        for (int ni = 0; ni < 2; ++ni) {
            bg[ni] = *(const i32x4*)(Lr + 32768 + (wn * 32 + ni * 16 + lr) * 64 + swz);
            bu[ni] = *(const i32x4*)(Lr + 40960 + (wn * 32 + ni * 16 + lr) * 64 + swz);
        }
        if (st) { GLD16(gA0 + kk, Lw + ldst); GLD16(gA1 + kk, Lw + 8192 + ldst); }
        BARRIER();
        __builtin_amdgcn_s_setprio(1);
        #pragma unroll
        for (int mi = 0; mi < 4; ++mi)
            #pragma unroll
            for (int ni = 0; ni < 2; ++ni) {
                accg[mi][ni] = __builtin_amdgcn_mfma_i32_16x16x64_i8(a[mi], bg[ni], accg[mi][ni], 0, 0, 0);
                accu[mi][ni] = __builtin_amdgcn_mfma_i32_16x16x64_i8(a[mi], bu[ni], accu[mi][ni], 0, 0, 0);
            }
        __builtin_amdgcn_s_setprio(0);
        BARRIER();

        // ---- p2 ----
        #pragma unroll
        for (int mi = 0; mi < 4; ++mi)
            a[mi] = *(const i32x4*)(Lr + (wm * 128 + 64 + mi * 16 + lr) * 64 + swz);
        if (st) { GLD16(gG + kk, Lw + 32768 + ldst); GLD16(gU + kk, Lw + 40960 + ldst); }
        BARRIER();
        __builtin_amdgcn_s_setprio(1);
        #pragma unroll
        for (int mi = 0; mi < 4; ++mi)
            #pragma unroll
            for (int ni = 0; ni < 2; ++ni) {
                accg[4 + mi][ni] = __builtin_amdgcn_mfma_i32_16x16x64_i8(a[mi], bg[ni], accg[4 + mi][ni], 0, 0, 0);
                accu[4 + mi][ni] = __builtin_amdgcn_mfma_i32_16x16x64_i8(a[mi], bu[ni], accu[4 + mi][ni], 0, 0, 0);
            }
        __builtin_amdgcn_s_setprio(0);
        if (st) { VMCNT4(); } else { VMCNT0(); }
        BARRIER();

        // ---- p3 ----
        #pragma unroll
        for (int mi = 0; mi < 4; ++mi)
            a[mi] = *(const i32x4*)(Lr + 16384 + (wm * 128 + mi * 16 + lr) * 64 + swz);
        #pragma unroll
        for (int ni = 0; ni < 2; ++ni) {
            bg[ni] = *(const i32x4*)(Lr + 49152 + (wn * 32 + ni * 16 + lr) * 64 + swz);
            bu[ni] = *(const i32x4*)(Lr + 57344 + (wn * 32 + ni * 16 + lr) * 64 + swz);
        }
        if (st) { GLD16(gA0 + kk + 64, Lw + 16384 + ldst); GLD16(gA1 + kk + 64, Lw + 24576 + ldst); }
        BARRIER();
        __builtin_amdgcn_s_setprio(1);
        #pragma unroll
        for (int mi = 0; mi < 4; ++mi)
            #pragma unroll
            for (int ni = 0; ni < 2; ++ni) {
                accg[mi][ni] = __builtin_amdgcn_mfma_i32_16x16x64_i8(a[mi], bg[ni], accg[mi][ni], 0, 0, 0);
                accu[mi][ni] = __builtin_amdgcn_mfma_i32_16x16x64_i8(a[mi], bu[ni], accu[mi][ni], 0, 0, 0);
            }
        __builtin_amdgcn_s_setprio(0);
        BARRIER();

        // ---- p4 ----
        #pragma unroll
        for (int mi = 0; mi < 4; ++mi)
            a[mi] = *(const i32x4*)(Lr + 16384 + (wm * 128 + 64 + mi * 16 + lr) * 64 + swz);
        if (st) { GLD16(gG + kk + 64, Lw + 49152 + ldst); GLD16(gU + kk + 64, Lw + 57344 + ldst); }
        BARRIER();
        __builtin_amdgcn_s_setprio(1);
        #pragma unroll
        for (int mi = 0; mi < 4; ++mi)
            #pragma unroll
            for (int ni = 0; ni < 2; ++ni) {
                accg[4 + mi][ni] = __builtin_amdgcn_mfma_i32_16x16x64_i8(a[mi], bg[ni], accg[4 + mi][ni], 0, 0, 0);
                accu[4 + mi][ni] = __builtin_amdgcn_mfma_i32_16x16x64_i8(a[mi], bu[ni], accu[4 + mi][ni], 0, 0, 0);
            }
        __builtin_amdgcn_s_setprio(0);
        if (st) { VMCNT4(); }
        BARRIER();
    }

    // ---- epilogue (single compute pass) ----
    // pass 1: h = SwiGLU once -> f32 into LDS tile [256 rows][128 cols] (exactly 128 KB); track lmax in regs
    const float s_x = sx[0];
    float lmax = 0.f;
    #pragma unroll
    for (int ni = 0; ni < 2; ++ni) {
        const int nl = wn * 32 + ni * 16 + lr;
        const float fg = s_x * sg[n0 + nl];
        const float fu = s_x * su[n0 + nl];
        #pragma unroll
        for (int mi = 0; mi < 8; ++mi) {
            const int rowb = wm * 128 + mi * 16 + lk * 4;
            #pragma unroll
            for (int r = 0; r < 4; ++r) {
                float g = (float)accg[mi][ni][r] * fg;
                float u = (float)accu[mi][ni][r] * fu;
                float h = g * u / (1.f + expf(-g));
                *(float*)(lds + ((rowb + r) << 9) + (nl << 2)) = h;
                lmax = fmaxf(lmax, fabsf(h));
            }
        }
    }
    #pragma unroll
    for (int off = 32; off > 0; off >>= 1) lmax = fmaxf(lmax, __shfl_xor(lmax, off, 64));
    // per-block bmax via this block's private sblk slot (pre-zeroed; values >= 0 so uint-max == float-max)
    unsigned int* slot = (unsigned int*)&sblk[mt * 22 + nt];
    if (lane == 0) atomicMax(slot, __float_as_uint(lmax));
    BARRIER();
    const float bmax = __uint_as_float(*slot);
    if (tid == 0) atomicMax(maxh, __float_as_uint(bmax));
    const float qs = 32766.f / fmaxf(bmax, 1e-20f);
    // pass 2: strided LDS read (conflict-free), quantize to int16, packed dword coalesced stores
    uint* H16u = (uint*)H16;
    #pragma unroll
    for (int k = 0; k < 32; ++k) {
        const int fidx = 2 * (tid + k * 512);        // even float index in [0, 32768)
        const int row = fidx >> 7, col = fidx & 127;
        const float2 hv = *(const float2*)(lds + (fidx << 2));
        const int s0 = (int)rintf(hv.x * qs), s1 = (int)rintf(hv.y * qs);
        H16u[((size_t)(m0 + row) * N + n0 + col) >> 1] = (s0 & 0xFFFF) | (s1 << 16);
    }
}

// ================= GEMM2 — unchanged R7 8-phase structure, 256x256 =================
__global__ __launch_bounds__(512, 2) void k_gemm2_i8(
    const int8_t* __restrict__ Aq, const int8_t* __restrict__ Bw,
    const float* __restrict__ sw, const float* __restrict__ sh,
    float* __restrict__ Out)
{
    constexpr int K = 2816, N = 1024, NT = K / 128, BUF = 65536;   // NT = 22
    __shared__ int8_t lds[2 * BUF];

    const int chunk = gridDim.x >> 3;                // grid = 1024 = 8*128
    const int wg = ((int)blockIdx.x & 7) * chunk + ((int)blockIdx.x >> 3);
    const int mt = wg >> 2, nt = wg & 3;
    const int m0 = mt * 256, n0 = nt * 256;
    const int tid = threadIdx.x;
    const int wid = tid >> 6, lane = tid & 63;
    const int wm = wid >> 2, wn = wid & 3;
    const int lr = lane & 15, lk = lane >> 4;

    const int srow = tid >> 2;
    const int scol = ((tid & 3) ^ ((srow >> 1) & 3)) << 4;
    const int8_t* gA0 = Aq + (size_t)(m0 + srow) * K + scol;
    const int8_t* gA1 = gA0 + (size_t)128 * K;
    const int8_t* gB0 = Bw + (size_t)(n0 + srow) * K + scol;
    const int8_t* gB1 = gB0 + (size_t)128 * K;
    const int ldst = wid << 10;

    const int swz = (lk ^ ((lr >> 1) & 3)) << 4;

    i32x4 acc[8][4] = {};

    {
        int8_t* Lw = &lds[0];
        GLD16(gA0,      Lw + ldst);         GLD16(gA1,      Lw + 8192  + ldst);
        GLD16(gB0,      Lw + 32768 + ldst); GLD16(gB1,      Lw + 40960 + ldst);
        GLD16(gA0 + 64, Lw + 16384 + ldst); GLD16(gA1 + 64, Lw + 24576 + ldst);
        GLD16(gB0 + 64, Lw + 49152 + ldst); GLD16(gB1 + 64, Lw + 57344 + ldst);
    }
    VMCNT4();
    BARRIER();

    for (int t = 0; t < NT; ++t) {
        const bool st = (t + 1 < NT);
        const size_t kk = (size_t)(t + 1) * 128;
        const int8_t* Lr = &lds[(t & 1) * BUF];
        int8_t* Lw = &lds[((t + 1) & 1) * BUF];
        i32x4 a[4], b[4];

        // ---- p1 ----
        #pragma unroll
        for (int mi = 0; mi < 4; ++mi)
            a[mi] = *(const i32x4*)(Lr + (wm * 128 + mi * 16 + lr) * 64 + swz);
        #pragma unroll
        for (int ni = 0; ni < 4; ++ni)
            b[ni] = *(const i32x4*)(Lr + 32768 + (wn * 64 + ni * 16 + lr) * 64 + swz);
        if (st) { GLD16(gA0 + kk, Lw + ldst); GLD16(gA1 + kk, Lw + 8192 + ldst); }
        BARRIER();
        __builtin_amdgcn_s_setprio(1);
        #pragma unroll
        for (int mi = 0; mi < 4; ++mi)
            #pragma unroll
            for (int ni = 0; ni < 4; ++ni)
                acc[mi][ni] = __builtin_amdgcn_mfma_i32_16x16x64_i8(a[mi], b[ni], acc[mi][ni], 0, 0, 0);
        __builtin_amdgcn_s_setprio(0);
        BARRIER();

        // ---- p2 ----
        #pragma unroll
        for (int mi = 0; mi < 4; ++mi)
            a[mi] = *(const i32x4*)(Lr + (wm * 128 + 64 + mi * 16 + lr) * 64 + swz);
        if (st) { GLD16(gB0 + kk, Lw + 32768 + ldst); GLD16(gB1 + kk, Lw + 40960 + ldst); }
        BARRIER();
        __builtin_amdgcn_s_setprio(1);
        #pragma unroll
        for (int mi = 0; mi < 4; ++mi)
            #pragma unroll
            for (int ni = 0; ni < 4; ++ni)
                acc[4 + mi][ni] = __builtin_amdgcn_mfma_i32_16x16x64_i8(a[mi], b[ni], acc[4 + mi][ni], 0, 0, 0);
        __builtin_amdgcn_s_setprio(0);
        if (st) { VMCNT4(); } else { VMCNT0(); }
        BARRIER();

        // ---- p3 ----
        #pragma unroll
        for (int mi = 0; mi < 4; ++mi)
            a[mi] = *(const i32x4*)(Lr + 16384 + (wm * 128 + mi * 16 + lr) * 64 + swz);
        #pragma unroll
        for (int ni = 0; ni < 4; ++ni)
            b[ni] = *(const i32x4*)(Lr + 49152 + (wn * 64 + ni * 16 + lr) * 64 + swz);
        if (st) { GLD16(gA0 + kk + 64, Lw + 16384 + ldst); GLD16(gA1 + kk + 64, Lw + 24576 + ldst); }
        BARRIER();
        __builtin_amdgcn_s_setprio(1);
        #pragma unroll
        for (int mi = 0; mi < 4; ++mi)
            #pragma unroll
            for (int ni = 0; ni < 4; ++ni)
                acc[mi][ni] = __builtin_amdgcn_mfma_i32_16x16x64_i8(a[mi], b[ni], acc[mi][ni], 0, 0, 0);
        __builtin_amdgcn_s_setprio(0);
        BARRIER();

        // ---- p4 ----
        #pragma unroll
        for (int mi = 0; mi < 4; ++mi)
            a[mi] = *(const i32x4*)(Lr + 16384 + (wm * 128 + 64 + mi * 16 + lr) * 64 + swz);
        if (st) { GLD16(gB0 + kk + 64, Lw + 49152 + ldst); GLD16(gB1 + kk + 64, Lw + 57344 + ldst); }
        BARRIER();
        __builtin_amdgcn_s_setprio(1);
        #pragma unroll
        for (int mi = 0; mi < 4; ++mi)
            #pragma unroll
            for (int ni = 0; ni < 4; ++ni)
                acc[4 + mi][ni] = __builtin_amdgcn_mfma_i32_16x16x64_i8(a[mi], b[ni], acc[4 + mi][ni], 0, 0, 0);
        __builtin_amdgcn_s_setprio(0);
        if (st) { VMCNT4(); }
        BARRIER();
    }

    const float s_h = sh[0];
    #pragma unroll
    for (int ni = 0; ni < 4; ++ni) {
        const int n = n0 + wn * 64 + ni * 16 + lr;
        const float f = s_h * sw[n];
        #pragma unroll
        for (int mi = 0; mi < 8; ++mi) {
            const int mb = m0 + wm * 128 + mi * 16 + lk * 4;
            #pragma unroll
            for (int r = 0; r < 4; ++r)
                Out[(size_t)(mb + r) * N + n] = (float)acc[mi][ni][r] * f;
        }
    }
}

extern "C" void kernel_launch(void* const* d_in, const int* in_sizes, int n_in,
                              void* d_out, int out_size, void* d_ws, size_t ws_size,
                              hipStream_t stream) {
    const float* x       = (const float*)d_in[0];
    const float* clip_x  = (const float*)d_in[1];
    const float* clip_dn = (const float*)d_in[2];
    const float* w_gate  = (const float*)d_in[3];
    const float* w_up    = (const float*)d_in[4];
    const float* w_down  = (const float*)d_in[5];
    float* out = (float*)d_out;

    const int Hd = 1024, Id = 2816;
    const int M = in_sizes[0] / Hd;                  // 65536
    const size_t nx = (size_t)M * Hd;
    const size_t nh = (size_t)M * Id;

    char* ws = (char*)d_ws;
    size_t off = 0;
    auto alloc = [&](size_t bytes) -> char* {
        char* p = ws + off;
        off = (off + bytes + 255) & ~(size_t)255;
        return p;
    };
    unsigned int* max_slots = (unsigned int*)alloc(8);   // [0]=max|x|, [1]=max|h|
    float* sxp = (float*)alloc(8);                       // [0]=scale, [1]=1/scale
    float* shp = (float*)alloc(8);
    int8_t* qx  = (int8_t*)alloc(nx);
    int8_t* qwg = (int8_t*)alloc((size_t)Id * Hd);
    int8_t* qwu = (int8_t*)alloc((size_t)Id * Hd);
    int8_t* qwd = (int8_t*)alloc((size_t)Hd * Id);
    float* swg = (float*)alloc((size_t)Id * 4);
    float* swu = (float*)alloc((size_t)Id * 4);
    float* swd = (float*)alloc((size_t)Hd * 4);
    int8_t* qh = (int8_t*)alloc(nh);
    short* h16 = (short*)alloc(nh * 2);
    const size_t sblk_bytes = (size_t)(M / 256) * 22 * 4;
    float* sblk = (float*)alloc(sblk_bytes);

    hipMemsetAsync(max_slots, 0, 8, stream);
    hipMemsetAsync(sblk, 0, sblk_bytes, stream);     // per-block bmax slots (atomicMax targets)

    k_absmax<<<4096, 256, 0, stream>>>(x, nx / 4, &max_slots[0]);
    k_scale<<<1, 1, 0, stream>>>(clip_x, &max_slots[0], sxp);
    k_quant_f32_i8<<<2048, 256, 0, stream>>>(x, (int4*)qx, sxp, nx / 16);
    k_quant_w_i8<<<Id, 256, 0, stream>>>(w_gate, qwg, swg, Hd);
    k_quant_w_i8<<<Id, 256, 0, stream>>>(w_up, qwu, swu, Hd);
    k_quant_w_i8<<<Hd, 256, 0, stream>>>(w_down, qwd, swd, Id);

    const int g1grid = (M / 256) * 11;               // per nt-half
    k_gemm1_i8<<<g1grid, 512, 0, stream>>>(qx, qwg, qwu, swg, swu, sxp, h16, sblk, &max_slots[1], 0);
    k_gemm1_i8<<<g1grid, 512, 0, stream>>>(qx, qwg, qwu, swg, swu, sxp, h16, sblk, &max_slots[1], 11);
    k_scale<<<1, 1, 0, stream>>>(clip_dn, &max_slots[1], shp);
    k_quant_h16_i8<<<4096, 256, 0, stream>>>(h16, sblk, shp, (int4*)qh, nh / 16);

    k_gemm2_i8<<<(M / 256) * (Hd / 256), 512, 0, stream>>>(qh, qwd, swd, shp, out);
}

// Round 9
// 1136.169 us; speedup vs baseline: 5.2400x; 1.0176x over previous
//
#include <hip/hip_runtime.h>
#include <stdint.h>

typedef __attribute__((ext_vector_type(4))) int i32x4;

typedef const __attribute__((address_space(1))) void gvoid_t;
typedef __attribute__((address_space(3))) void lvoid_t;

#define GLD16(g, l) __builtin_amdgcn_global_load_lds((gvoid_t*)(g), (lvoid_t*)(l), 16, 0, 0)
#define FENCE() asm volatile("" ::: "memory")
#define BARRIER() do { FENCE(); __builtin_amdgcn_s_barrier(); FENCE(); } while (0)
#define SCHEDB() __builtin_amdgcn_sched_barrier(0)
#define GATE(n) asm volatile("s_waitcnt vmcnt(" #n ")\n\ts_barrier" ::: "memory")

__device__ inline int q1mul(float x, float r) {
    return (int)fminf(fmaxf(rintf(x * r), -128.f), 127.f);
}
__device__ inline int q1div(float x, float s) {
    return (int)fminf(fmaxf(rintf(x / s), -128.f), 127.f);
}
__device__ inline int pack4(float4 v, float r) {
    return (q1mul(v.x, r) & 255) | ((q1mul(v.y, r) & 255) << 8) |
           ((q1mul(v.z, r) & 255) << 16) | ((q1mul(v.w, r) & 255) << 24);
}

// ---------------- global absmax (4 independent chains) ----------------
__global__ void k_absmax(const float* __restrict__ x, size_t n4, unsigned int* __restrict__ out) {
    size_t S = (size_t)gridDim.x * blockDim.x;
    size_t i = (size_t)blockIdx.x * blockDim.x + threadIdx.x;
    const float4* x4 = (const float4*)x;
    float m0 = 0.f, m1 = 0.f, m2 = 0.f, m3 = 0.f;
    for (; i + 3 * S < n4; i += 4 * S) {
        float4 v0 = x4[i], v1 = x4[i + S], v2 = x4[i + 2 * S], v3 = x4[i + 3 * S];
        m0 = fmaxf(m0, fmaxf(fmaxf(fabsf(v0.x), fabsf(v0.y)), fmaxf(fabsf(v0.z), fabsf(v0.w))));
        m1 = fmaxf(m1, fmaxf(fmaxf(fabsf(v1.x), fabsf(v1.y)), fmaxf(fabsf(v1.z), fabsf(v1.w))));
        m2 = fmaxf(m2, fmaxf(fmaxf(fabsf(v2.x), fabsf(v2.y)), fmaxf(fabsf(v2.z), fabsf(v2.w))));
        m3 = fmaxf(m3, fmaxf(fmaxf(fabsf(v3.x), fabsf(v3.y)), fmaxf(fabsf(v3.z), fabsf(v3.w))));
    }
    for (; i < n4; i += S) {
        float4 v = x4[i];
        m0 = fmaxf(m0, fmaxf(fmaxf(fabsf(v.x), fabsf(v.y)), fmaxf(fabsf(v.z), fabsf(v.w))));
    }
    float m = fmaxf(fmaxf(m0, m1), fmaxf(m2, m3));
    #pragma unroll
    for (int off = 32; off > 0; off >>= 1) m = fmaxf(m, __shfl_xor(m, off, 64));
    if ((threadIdx.x & 63) == 0) atomicMax(out, __float_as_uint(m));
}

// ---------------- scale finalize ----------------
__global__ void k_scale(const float* __restrict__ clip, const unsigned int* __restrict__ maxbits,
                        float* __restrict__ s_out) {
    float m = __uint_as_float(*maxbits);
    float sig = 1.f / (1.f + expf(-clip[0]));
    float s = sig * m / 127.f;
    s_out[0] = s;
    s_out[1] = 1.f / s;
}

// ---------------- quantize fp32 -> packed int8 ----------------
__global__ void k_quant_f32_i8(const float* __restrict__ in, int4* __restrict__ out,
                               const float* __restrict__ sptr, size_t n16) {
    float r = sptr[1];
    size_t S = (size_t)gridDim.x * blockDim.x;
    size_t i = (size_t)blockIdx.x * blockDim.x + threadIdx.x;
    const float4* in4 = (const float4*)in;
    for (; i < n16; i += S) {
        float4 v0 = in4[4 * i], v1 = in4[4 * i + 1], v2 = in4[4 * i + 2], v3 = in4[4 * i + 3];
        int4 o;
        o.x = pack4(v0, r); o.y = pack4(v1, r); o.z = pack4(v2, r); o.w = pack4(v3, r);
        out[i] = o;
    }
}

// ---------------- quantize h16 (per-block scale) -> packed int8 ----------------
__global__ void k_quant_h16_i8(const short* __restrict__ h16, const float* __restrict__ sblk,
                               const float* __restrict__ sh, int4* __restrict__ qh, size_t nchunks) {
    const float rh = sh[1] * (1.f / 32766.f);
    size_t S = (size_t)gridDim.x * blockDim.x;
    size_t i = (size_t)blockIdx.x * blockDim.x + threadIdx.x;
    for (; i < nchunks; i += S) {
        int row = (int)(i / 176);
        int col = (int)(i - (size_t)row * 176) * 16;
        float f = sblk[(row >> 8) * 22 + (col >> 7)] * rh;
        const int4* p = (const int4*)(h16 + (size_t)row * 2816 + col);
        int4 lo = p[0], hi = p[1];
        int w[8] = {lo.x, lo.y, lo.z, lo.w, hi.x, hi.y, hi.z, hi.w};
        int ob[4];
        #pragma unroll
        for (int j = 0; j < 4; ++j) {
            int q0 = q1mul((float)(short)(w[2 * j] & 0xFFFF), f);
            int q1 = q1mul((float)(short)(w[2 * j] >> 16), f);
            int q2 = q1mul((float)(short)(w[2 * j + 1] & 0xFFFF), f);
            int q3 = q1mul((float)(short)(w[2 * j + 1] >> 16), f);
            ob[j] = (q0 & 255) | ((q1 & 255) << 8) | ((q2 & 255) << 16) | ((q3 & 255) << 24);
        }
        int4 o; o.x = ob[0]; o.y = ob[1]; o.z = ob[2]; o.w = ob[3];
        qh[i] = o;
    }
}

// ---------------- per-row weight quantization ----------------
__global__ void k_quant_w_i8(const float* __restrict__ W, int8_t* __restrict__ Q,
                             float* __restrict__ srow, int cols) {
    int row = blockIdx.x;
    const float* w = W + (size_t)row * cols;
    float m = 0.f;
    for (int c = threadIdx.x; c < cols; c += 256) m = fmaxf(m, fabsf(w[c]));
    #pragma unroll
    for (int off = 32; off > 0; off >>= 1) m = fmaxf(m, __shfl_xor(m, off, 64));
    __shared__ float red[4];
    if ((threadIdx.x & 63) == 0) red[threadIdx.x >> 6] = m;
    __syncthreads();
    if (threadIdx.x == 0) {
        float mm = fmaxf(fmaxf(red[0], red[1]), fmaxf(red[2], red[3]));
        red[0] = mm / 127.f;
        srow[row] = mm / 127.f;
    }
    __syncthreads();
    float s = red[0];
    for (int c = threadIdx.x; c < cols; c += 256)
        Q[(size_t)row * cols + c] = (int8_t)q1div(w[c], s);
}

#define MFMA_G1(AF, BG, BU, OFF)                                                              \
    _Pragma("unroll")                                                                         \
    for (int mi = 0; mi < 4; ++mi) {                                                          \
        _Pragma("unroll")                                                                     \
        for (int ni = 0; ni < 2; ++ni) {                                                      \
            accg[(OFF) + mi][ni] = __builtin_amdgcn_mfma_i32_16x16x64_i8(AF[mi], BG[ni], accg[(OFF) + mi][ni], 0, 0, 0); \
            accu[(OFF) + mi][ni] = __builtin_amdgcn_mfma_i32_16x16x64_i8(AF[mi], BU[ni], accu[(OFF) + mi][ni], 0, 0, 0); \
        }                                                                                     \
    }

// ================= GEMM1 (gate+up) — register read-ahead pipeline, 2 barriers/K-tile =================
// Tile 256x128(g,u each), BK=128 (two 64B k-slabs). LDS/buf 64K: A0@0 A1@16K G0@32K U0@40K G1@48K U1@56K.
// Each phase's ds_reads load the NEXT phase's fragments -> LDS pipe runs under the MFMA window.
// Hazards: intra-tile reads(buf t) vs writes(buf t+1) disjoint; cross-tile pairs separated by
// the two counted-vmcnt gates (see per-gate derivations below).
__global__ __launch_bounds__(512, 2) void k_gemm1_i8(
    const int8_t* __restrict__ Aq, const int8_t* __restrict__ Bg, const int8_t* __restrict__ Bu,
    const float* __restrict__ sg, const float* __restrict__ su, const float* __restrict__ sx,
    short* __restrict__ H16, float* __restrict__ sblk, unsigned int* __restrict__ maxh,
    int nt_base)
{
    constexpr int K = 1024, N = 2816, NT = K / 128, BUF = 65536;
    __shared__ int8_t lds[2 * BUF];

    const int wgl = (int)blockIdx.x >> 3;
    const int xcd = (int)blockIdx.x & 7;
    const int mtspan = (int)(gridDim.x >> 3) / 11;
    const int mt = xcd * mtspan + wgl / 11;
    const int nt = nt_base + wgl % 11;
    const int m0 = mt * 256, n0 = nt * 128;
    const int tid = threadIdx.x;
    const int wid = tid >> 6, lane = tid & 63;
    const int wm = wid >> 2, wn = wid & 3;
    const int lr = lane & 15, lk = lane >> 4;

    const int srow = tid >> 2;
    const int scol = ((tid & 3) ^ ((srow >> 1) & 3)) << 4;
    const int8_t* gA0 = Aq + (size_t)(m0 + srow) * K + scol;
    const int8_t* gA1 = gA0 + (size_t)128 * K;
    const int8_t* gG  = Bg + (size_t)(n0 + srow) * K + scol;
    const int8_t* gU  = Bu + (size_t)(n0 + srow) * K + scol;
    const int ldst = wid << 10;

    const int swz = (lk ^ ((lr >> 1) & 3)) << 4;
    const int aoff = (wm * 128 + lr) * 64 + swz;          // + mi*1024; mh1 +4096; A1 +16384
    const int boffG = 32768 + (wn * 32 + lr) * 64 + swz;  // + ni*1024; G1/U1 +16384
    const int boffU = 40960 + (wn * 32 + lr) * 64 + swz;

    i32x4 accg[8][2] = {};
    i32x4 accu[8][2] = {};
    i32x4 aA[4], aB[4], bgA[2], buA[2], bgB[2], buB[2];

    // prologue: tile0 GLD order = A0,G0U0 | A1,G1U1 (second group acts as "pC(-1) staging")
    {
        int8_t* Lw = &lds[0];
        GLD16(gA0,      Lw + ldst);         GLD16(gA1,      Lw + 8192  + ldst);
        GLD16(gG,       Lw + 32768 + ldst); GLD16(gU,       Lw + 40960 + ldst);
        GLD16(gA0 + 64, Lw + 16384 + ldst); GLD16(gA1 + 64, Lw + 24576 + ldst);
        GLD16(gG  + 64, Lw + 49152 + ldst); GLD16(gU  + 64, Lw + 57344 + ldst);
    }
    GATE(4);                                              // A0,G0U0(0) landed for everyone
    {
        const int8_t* Lr = &lds[0];
        #pragma unroll
        for (int mi = 0; mi < 4; ++mi) aA[mi] = *(const i32x4*)(Lr + aoff + mi * 1024);
        #pragma unroll
        for (int ni = 0; ni < 2; ++ni) {
            bgA[ni] = *(const i32x4*)(Lr + boffG + ni * 1024);
            buA[ni] = *(const i32x4*)(Lr + boffU + ni * 1024);
        }
    }

    for (int t = 0; t < NT; ++t) {
        const bool st = (t + 1 < NT);
        const int8_t* Lr = &lds[(t & 1) * BUF];
        int8_t* Lw = &lds[((t + 1) & 1) * BUF];
        const size_t kk = (size_t)(t + 1) * 128;

        // pA: read A0mh1->aB; stage A0(t+1); MFMA(A0mh0 x G0U0 -> quad0)
        #pragma unroll
        for (int mi = 0; mi < 4; ++mi) aB[mi] = *(const i32x4*)(Lr + aoff + 4096 + mi * 1024);
        if (st) { GLD16(gA0 + kk, Lw + ldst); GLD16(gA1 + kk, Lw + 8192 + ldst); }
        SCHEDB();
        __builtin_amdgcn_s_setprio(1);
        MFMA_G1(aA, bgA, buA, 0);
        __builtin_amdgcn_s_setprio(0);
        // gate2: pB reads A1,G1U1(t) staged in pC(t-1). outstanding = pC(t-1)4 + pA2 -> vmcnt(2).
        if (st) { GATE(2); } else { GATE(0); }

        // pB: read A1mh0->aA, G1U1->bgB/buB; stage G0U0(t+1); MFMA(A0mh1 x G0U0 -> quad4)
        #pragma unroll
        for (int mi = 0; mi < 4; ++mi) aA[mi] = *(const i32x4*)(Lr + 16384 + aoff + mi * 1024);
        #pragma unroll
        for (int ni = 0; ni < 2; ++ni) {
            bgB[ni] = *(const i32x4*)(Lr + 16384 + boffG + ni * 1024);
            buB[ni] = *(const i32x4*)(Lr + 16384 + boffU + ni * 1024);
        }
        if (st) { GLD16(gG + kk, Lw + 32768 + ldst); GLD16(gU + kk, Lw + 40960 + ldst); }
        SCHEDB();
        __builtin_amdgcn_s_setprio(1);
        MFMA_G1(aB, bgA, buA, 4);
        __builtin_amdgcn_s_setprio(0);

        // pC: read A1mh1->aB; stage A1(t+1)+G1U1(t+1); MFMA(A1mh0 x G1U1 -> quad0)
        #pragma unroll
        for (int mi = 0; mi < 4; ++mi) aB[mi] = *(const i32x4*)(Lr + 16384 + aoff + 4096 + mi * 1024);
        if (st) { GLD16(gA0 + kk + 64, Lw + 16384 + ldst); GLD16(gA1 + kk + 64, Lw + 24576 + ldst);
                  GLD16(gG + kk + 64, Lw + 49152 + ldst);  GLD16(gU + kk + 64, Lw + 57344 + ldst); }
        SCHEDB();
        __builtin_amdgcn_s_setprio(1);
        MFMA_G1(aA, bgB, buB, 0);
        __builtin_amdgcn_s_setprio(0);
        // gate1: pD reads A0,G0U0(t+1) staged in pA/pB(t). outstanding = pA2+pB2+pC4 -> vmcnt(4).
        if (st) { GATE(4); } else { GATE(0); }

        // pD: read A0mh0(t+1)->aA, G0U0(t+1)->bgA/buA (from Lw); MFMA(A1mh1 x G1U1 -> quad4)
        if (st) {
            #pragma unroll
            for (int mi = 0; mi < 4; ++mi) aA[mi] = *(const i32x4*)(Lw + aoff + mi * 1024);
            #pragma unroll
            for (int ni = 0; ni < 2; ++ni) {
                bgA[ni] = *(const i32x4*)(Lw + boffG + ni * 1024);
                buA[ni] = *(const i32x4*)(Lw + boffU + ni * 1024);
            }
        }
        SCHEDB();
        __builtin_amdgcn_s_setprio(1);
        MFMA_G1(aB, bgB, buB, 4);
        __builtin_amdgcn_s_setprio(0);
    }
    BARRIER();                                            // all LDS frag reads drained before h overwrites LDS

    // ---- epilogue (R8): single SwiGLU pass -> LDS -> coalesced int16 stores ----
    const float s_x = sx[0];
    float lmax = 0.f;
    #pragma unroll
    for (int ni = 0; ni < 2; ++ni) {
        const int nl = wn * 32 + ni * 16 + lr;
        const float fg = s_x * sg[n0 + nl];
        const float fu = s_x * su[n0 + nl];
        #pragma unroll
        for (int mi = 0; mi < 8; ++mi) {
            const int rowb = wm * 128 + mi * 16 + lk * 4;
            #pragma unroll
            for (int r = 0; r < 4; ++r) {
                float g = (float)accg[mi][ni][r] * fg;
                float u = (float)accu[mi][ni][r] * fu;
                float h = g * u / (1.f + expf(-g));
                *(float*)(lds + ((rowb + r) << 9) + (nl << 2)) = h;
                lmax = fmaxf(lmax, fabsf(h));
            }
        }
    }
    #pragma unroll
    for (int off = 32; off > 0; off >>= 1) lmax = fmaxf(lmax, __shfl_xor(lmax, off, 64));
    unsigned int* slot = (unsigned int*)&sblk[mt * 22 + nt];
    if (lane == 0) atomicMax(slot, __float_as_uint(lmax));
    BARRIER();
    const float bmax = __uint_as_float(*slot);
    if (tid == 0) atomicMax(maxh, __float_as_uint(bmax));
    const float qs = 32766.f / fmaxf(bmax, 1e-20f);
    uint* H16u = (uint*)H16;
    #pragma unroll
    for (int k = 0; k < 32; ++k) {
        const int fidx = 2 * (tid + k * 512);
        const int row = fidx >> 7, col = fidx & 127;
        const float2 hv = *(const float2*)(lds + (fidx << 2));
        const int s0 = (int)rintf(hv.x * qs), s1 = (int)rintf(hv.y * qs);
        H16u[((size_t)(m0 + row) * N + n0 + col) >> 1] = (s0 & 0xFFFF) | (s1 << 16);
    }
}

#define MFMA_G2(AF, BF, OFF)                                                                  \
    _Pragma("unroll")                                                                         \
    for (int mi = 0; mi < 4; ++mi) {                                                          \
        _Pragma("unroll")                                                                     \
        for (int ni = 0; ni < 4; ++ni)                                                        \
            acc[(OFF) + mi][ni] = __builtin_amdgcn_mfma_i32_16x16x64_i8(AF[mi], BF[ni], acc[(OFF) + mi][ni], 0, 0, 0); \
    }

// ================= GEMM2 — same read-ahead pipeline, 256x256 =================
// LDS/buf 64K: A0@0 A1@16K B0@32K B1@48K.
__global__ __launch_bounds__(512, 2) void k_gemm2_i8(
    const int8_t* __restrict__ Aq, const int8_t* __restrict__ Bw,
    const float* __restrict__ sw, const float* __restrict__ sh,
    float* __restrict__ Out)
{
    constexpr int K = 2816, N = 1024, NT = K / 128, BUF = 65536;   // NT = 22
    __shared__ int8_t lds[2 * BUF];

    const int chunk = gridDim.x >> 3;                // grid = 1024 = 8*128
    const int wg = ((int)blockIdx.x & 7) * chunk + ((int)blockIdx.x >> 3);
    const int mt = wg >> 2, nt = wg & 3;
    const int m0 = mt * 256, n0 = nt * 256;
    const int tid = threadIdx.x;
    const int wid = tid >> 6, lane = tid & 63;
    const int wm = wid >> 2, wn = wid & 3;
    const int lr = lane & 15, lk = lane >> 4;

    const int srow = tid >> 2;
    const int scol = ((tid & 3) ^ ((srow >> 1) & 3)) << 4;
    const int8_t* gA0 = Aq + (size_t)(m0 + srow) * K + scol;
    const int8_t* gA1 = gA0 + (size_t)128 * K;
    const int8_t* gB0 = Bw + (size_t)(n0 + srow) * K + scol;
    const int8_t* gB1 = gB0 + (size_t)128 * K;
    const int ldst = wid << 10;

    const int swz = (lk ^ ((lr >> 1) & 3)) << 4;
    const int aoff = (wm * 128 + lr) * 64 + swz;
    const int boff = 32768 + (wn * 64 + lr) * 64 + swz;   // + ni*1024; B1 +16384

    i32x4 acc[8][4] = {};
    i32x4 aA[4], aB[4], bA[4], bB[4];

    {
        int8_t* Lw = &lds[0];
        GLD16(gA0,      Lw + ldst);         GLD16(gA1,      Lw + 8192  + ldst);
        GLD16(gB0,      Lw + 32768 + ldst); GLD16(gB1,      Lw + 40960 + ldst);
        GLD16(gA0 + 64, Lw + 16384 + ldst); GLD16(gA1 + 64, Lw + 24576 + ldst);
        GLD16(gB0 + 64, Lw + 49152 + ldst); GLD16(gB1 + 64, Lw + 57344 + ldst);
    }
    GATE(4);
    {
        const int8_t* Lr = &lds[0];
        #pragma unroll
        for (int mi = 0; mi < 4; ++mi) aA[mi] = *(const i32x4*)(Lr + aoff + mi * 1024);
        #pragma unroll
        for (int ni = 0; ni < 4; ++ni) bA[ni] = *(const i32x4*)(Lr + boff + ni * 1024);
    }

    for (int t = 0; t < NT; ++t) {
        const bool st = (t + 1 < NT);
        const int8_t* Lr = &lds[(t & 1) * BUF];
        int8_t* Lw = &lds[((t + 1) & 1) * BUF];
        const size_t kk = (size_t)(t + 1) * 128;

        // pA
        #pragma unroll
        for (int mi = 0; mi < 4; ++mi) aB[mi] = *(const i32x4*)(Lr + aoff + 4096 + mi * 1024);
        if (st) { GLD16(gA0 + kk, Lw + ldst); GLD16(gA1 + kk, Lw + 8192 + ldst); }
        SCHEDB();
        __builtin_amdgcn_s_setprio(1);
        MFMA_G2(aA, bA, 0);
        __builtin_amdgcn_s_setprio(0);
        if (st) { GATE(2); } else { GATE(0); }

        // pB
        #pragma unroll
        for (int mi = 0; mi < 4; ++mi) aA[mi] = *(const i32x4*)(Lr + 16384 + aoff + mi * 1024);
        #pragma unroll
        for (int ni = 0; ni < 4; ++ni) bB[ni] = *(const i32x4*)(Lr + 16384 + boff + ni * 1024);
        if (st) { GLD16(gB0 + kk, Lw + 32768 + ldst); GLD16(gB1 + kk, Lw + 40960 + ldst); }
        SCHEDB();
        __builtin_amdgcn_s_setprio(1);
        MFMA_G2(aB, bA, 4);
        __builtin_amdgcn_s_setprio(0);

        // pC
        #pragma unroll
        for (int mi = 0; mi < 4; ++mi) aB[mi] = *(const i32x4*)(Lr + 16384 + aoff + 4096 + mi * 1024);
        if (st) { GLD16(gA0 + kk + 64, Lw + 16384 + ldst); GLD16(gA1 + kk + 64, Lw + 24576 + ldst);
                  GLD16(gB0 + kk + 64, Lw + 49152 + ldst); GLD16(gB1 + kk + 64, Lw + 57344 + ldst); }
        SCHEDB();
        __builtin_amdgcn_s_setprio(1);
        MFMA_G2(aA, bB, 0);
        __builtin_amdgcn_s_setprio(0);
        if (st) { GATE(4); } else { GATE(0); }

        // pD
        if (st) {
            #pragma unroll
            for (int mi = 0; mi < 4; ++mi) aA[mi] = *(const i32x4*)(Lw + aoff + mi * 1024);
            #pragma unroll
            for (int ni = 0; ni < 4; ++ni) bA[ni] = *(const i32x4*)(Lw + boff + ni * 1024);
        }
        SCHEDB();
        __builtin_amdgcn_s_setprio(1);
        MFMA_G2(aB, bB, 4);
        __builtin_amdgcn_s_setprio(0);
    }

    const float s_h = sh[0];
    #pragma unroll
    for (int ni = 0; ni < 4; ++ni) {
        const int n = n0 + wn * 64 + ni * 16 + lr;
        const float f = s_h * sw[n];
        #pragma unroll
        for (int mi = 0; mi < 8; ++mi) {
            const int mb = m0 + wm * 128 + mi * 16 + lk * 4;
            #pragma unroll
            for (int r = 0; r < 4; ++r)
                Out[(size_t)(mb + r) * N + n] = (float)acc[mi][ni][r] * f;
        }
    }
}

extern "C" void kernel_launch(void* const* d_in, const int* in_sizes, int n_in,
                              void* d_out, int out_size, void* d_ws, size_t ws_size,
                              hipStream_t stream) {
    const float* x       = (const float*)d_in[0];
    const float* clip_x  = (const float*)d_in[1];
    const float* clip_dn = (const float*)d_in[2];
    const float* w_gate  = (const float*)d_in[3];
    const float* w_up    = (const float*)d_in[4];
    const float* w_down  = (const float*)d_in[5];
    float* out = (float*)d_out;

    const int Hd = 1024, Id = 2816;
    const int M = in_sizes[0] / Hd;                  // 65536
    const size_t nx = (size_t)M * Hd;
    const size_t nh = (size_t)M * Id;

    char* ws = (char*)d_ws;
    size_t off = 0;
    auto alloc = [&](size_t bytes) -> char* {
        char* p = ws + off;
        off = (off + bytes + 255) & ~(size_t)255;
        return p;
    };
    unsigned int* max_slots = (unsigned int*)alloc(8);   // [0]=max|x|, [1]=max|h|
    float* sxp = (float*)alloc(8);
    float* shp = (float*)alloc(8);
    int8_t* qx  = (int8_t*)alloc(nx);
    int8_t* qwg = (int8_t*)alloc((size_t)Id * Hd);
    int8_t* qwu = (int8_t*)alloc((size_t)Id * Hd);
    int8_t* qwd = (int8_t*)alloc((size_t)Hd * Id);
    float* swg = (float*)alloc((size_t)Id * 4);
    float* swu = (float*)alloc((size_t)Id * 4);
    float* swd = (float*)alloc((size_t)Hd * 4);
    int8_t* qh = (int8_t*)alloc(nh);
    short* h16 = (short*)alloc(nh * 2);
    const size_t sblk_bytes = (size_t)(M / 256) * 22 * 4;
    float* sblk = (float*)alloc(sblk_bytes);

    hipMemsetAsync(max_slots, 0, 8, stream);
    hipMemsetAsync(sblk, 0, sblk_bytes, stream);

    k_absmax<<<4096, 256, 0, stream>>>(x, nx / 4, &max_slots[0]);
    k_scale<<<1, 1, 0, stream>>>(clip_x, &max_slots[0], sxp);
    k_quant_f32_i8<<<2048, 256, 0, stream>>>(x, (int4*)qx, sxp, nx / 16);
    k_quant_w_i8<<<Id, 256, 0, stream>>>(w_gate, qwg, swg, Hd);
    k_quant_w_i8<<<Id, 256, 0, stream>>>(w_up, qwu, swu, Hd);
    k_quant_w_i8<<<Hd, 256, 0, stream>>>(w_down, qwd, swd, Id);

    const int g1grid = (M / 256) * 11;               // per nt-half
    k_gemm1_i8<<<g1grid, 512, 0, stream>>>(qx, qwg, qwu, swg, swu, sxp, h16, sblk, &max_slots[1], 0);
    k_gemm1_i8<<<g1grid, 512, 0, stream>>>(qx, qwg, qwu, swg, swu, sxp, h16, sblk, &max_slots[1], 11);
    k_scale<<<1, 1, 0, stream>>>(clip_dn, &max_slots[1], shp);
    k_quant_h16_i8<<<4096, 256, 0, stream>>>(h16, sblk, shp, (int4*)qh, nh / 16);

    k_gemm2_i8<<<(M / 256) * (Hd / 256), 512, 0, stream>>>(qh, qwd, swd, shp, out);
}